// Round 6
// baseline (128.397 us; speedup 1.0000x reference)
//
#include <hip/hip_runtime.h>
#include <cstdint>

#define D_MODEL   768
#define D_STATE   64
#define D_INNER   1536
#define NHEADS    24
#define HEADDIM   64
#define D_PROJ    3248
#define BATCH     2
#define SEQ       1024
#define ROWS      (BATCH*SEQ)   // 2048
#define LN_EPS    1e-5f
#define A_FLOOR   1e-4f
#define QC        64            // chunk length
#define NCH       (SEQ/QC)      // 16
#define LDT       68            // padded LDS stride (floats)
#define NPAD_WIN  3328          // 3248 padded to multiple of 128

typedef __attribute__((ext_vector_type(8))) short short8;
typedef __attribute__((ext_vector_type(4))) float f32x4;

// round-to-nearest-even f32 -> bf16 bits
__device__ __forceinline__ unsigned short f2bf(float f) {
  union { float f; uint32_t u; } v; v.f = f;
  uint32_t r = (v.u + 0x7FFFu + ((v.u >> 16) & 1u)) >> 16;
  return (unsigned short)r;
}

__device__ __forceinline__ void gload_lds16(const void* g, void* l) {
  __builtin_amdgcn_global_load_lds(
      (const __attribute__((address_space(1))) unsigned int*)g,
      (__attribute__((address_space(3))) unsigned int*)l, 16, 0, 0);
}

// counted vmcnt wait (T4) — literal strings, compile-time dispatched
template <int N>
__device__ __forceinline__ void wait_vm() {
  static_assert(N == 0 || N == 2 || N == 3 || N == 4 || N == 6, "unsupported vmcnt");
  if constexpr (N == 0) asm volatile("s_waitcnt vmcnt(0)" ::: "memory");
  else if constexpr (N == 2) asm volatile("s_waitcnt vmcnt(2)" ::: "memory");
  else if constexpr (N == 3) asm volatile("s_waitcnt vmcnt(3)" ::: "memory");
  else if constexpr (N == 4) asm volatile("s_waitcnt vmcnt(4)" ::: "memory");
  else if constexpr (N == 6) asm volatile("s_waitcnt vmcnt(6)" ::: "memory");
}

// ---------------------------------------------------------------------------
// Fused casts: u (2048x768), Win (3248->3328 x768 zero-padded), Wout (768x1536)
// ---------------------------------------------------------------------------
__global__ __launch_bounds__(256) void cast_all_kernel(
    const float* __restrict__ u, const float* __restrict__ Win,
    const float* __restrict__ Wout, unsigned short* __restrict__ ubf,
    unsigned short* __restrict__ Winbf, unsigned short* __restrict__ Woutbf) {
  int b = blockIdx.x;
  const float* src; unsigned short* dst; int cols, srcRows, row;
  if (b < ROWS)                 { row = b;                    src = u;    dst = ubf;    cols = D_MODEL; srcRows = ROWS;   }
  else if (b < ROWS + NPAD_WIN) { row = b - ROWS;             src = Win;  dst = Winbf;  cols = D_MODEL; srcRows = D_PROJ; }
  else                          { row = b - ROWS - NPAD_WIN;  src = Wout; dst = Woutbf; cols = D_INNER; srcRows = D_MODEL;}
  const bool live = row < srcRows;
  for (int c = threadIdx.x * 4; c < cols; c += 256 * 4) {
    float4 v = make_float4(0.f, 0.f, 0.f, 0.f);
    if (live) v = *(const float4*)(src + (size_t)row * cols + c);
    ushort4 o;
    o.x = f2bf(v.x); o.y = f2bf(v.y); o.z = f2bf(v.z); o.w = f2bf(v.w);
    *(ushort4*)(dst + (size_t)row * cols + c) = o;
  }
}

// ---------------------------------------------------------------------------
// MFMA bf16 GEMM (NT), 4-buffer / prefetch-distance-3 / ONE barrier per iter:
//   prologue: stage(0->b0), stage(1->b1), stage(2->b2)
//   iter t:   vmcnt(2L | L | 0) ; s_barrier(+fence) ;
//             stage(t+3 -> buf[(t+3)&3]) ; ds_read+MFMA from buf[t&3]
// Tile-t loads get a ~3-iteration in-flight window (covers HBM latency).
// Write-after-read safety: buf[(t+3)&3] was read at iter t-1; the iter-t
// barrier proves every wave finished those reads (ds_read completes before
// its consuming MFMA, which precedes the barrier in program order).
// A (M,K) bf16 rm, B (N,K) bf16 rm, C (M,N) f32. 256 thr = 4 waves (2x2).
// ---------------------------------------------------------------------------
template <int TBM, int TBN>
__global__ __launch_bounds__(256) void gemm_bt_bf16(
    const unsigned short* __restrict__ A, const unsigned short* __restrict__ B,
    float* __restrict__ C, int M, int N, int K) {
  constexpr int MF = TBM / 32;
  constexpr int NF = TBN / 32;
  constexpr int NSA = TBM / 16;
  constexpr int NSB = TBN / 16;
  constexpr int LPW = (NSA + NSB) / 4;   // gload_lds per wave per tile (exact)
  static_assert((NSA + NSB) % 4 == 0, "segments must split evenly over waves");
  __shared__ unsigned short Asm[4][TBM * 32];
  __shared__ unsigned short Bsm[4][TBN * 32];

  const int tid = threadIdx.x;
  const int wv = tid >> 6, lane = tid & 63;
  const int bm = blockIdx.y * TBM, bn = blockIdx.x * TBN;
  const int wm = (wv & 1) * (TBM / 2);
  const int wn = (wv >> 1) * (TBN / 2);
  const int g = lane >> 4, r = lane & 15;

  f32x4 acc[MF][NF];
#pragma unroll
  for (int i = 0; i < MF; ++i)
#pragma unroll
    for (int j = 0; j < NF; ++j) acc[i][j] = (f32x4){0.f, 0.f, 0.f, 0.f};

  auto stage = [&](int k0, int buf) {
    for (int s = wv; s < NSA + NSB; s += 4) {
      if (s < NSA) {
        int chunk = s / (TBM / 64);
        int row0 = (s % (TBM / 64)) * 64;
        gload_lds16(A + (size_t)(bm + row0 + lane) * K + k0 + chunk * 8,
                    (void*)(&Asm[buf][s * 512]));
      } else {
        int s2 = s - NSA;
        int chunk = s2 / (TBN / 64);
        int row0 = (s2 % (TBN / 64)) * 64;
        gload_lds16(B + (size_t)(bn + row0 + lane) * K + k0 + chunk * 8,
                    (void*)(&Bsm[buf][s2 * 512]));
      }
    }
  };

  const int kTiles = K >> 5;   // 24 or 48 here (>= 3)
  stage(0, 0);
  stage(32, 1);
  stage(64, 2);

  for (int t = 0; t < kTiles; ++t) {
    const int cur = t & 3;
    // younger staged tiles at this point: min(2, kTiles-1-t)
    if (t + 2 < kTiles)      wait_vm<2 * LPW>();
    else if (t + 1 < kTiles) wait_vm<LPW>();
    else                     wait_vm<0>();
    __builtin_amdgcn_s_barrier();
    asm volatile("" ::: "memory");   // s_barrier is IntrNoMem: fence reordering

    if (t + 3 < kTiles) stage((t + 3) << 5, (t + 3) & 3);

    short8 a[MF], b[NF];
#pragma unroll
    for (int mf = 0; mf < MF; ++mf)
      a[mf] = *(const short8*)&Asm[cur][g * TBM * 8 + (wm + mf * 16 + r) * 8];
#pragma unroll
    for (int nf = 0; nf < NF; ++nf)
      b[nf] = *(const short8*)&Bsm[cur][g * TBN * 8 + (wn + nf * 16 + r) * 8];
#pragma unroll
    for (int mf = 0; mf < MF; ++mf)
#pragma unroll
      for (int nf = 0; nf < NF; ++nf)
        acc[mf][nf] = __builtin_amdgcn_mfma_f32_16x16x32_bf16(a[mf], b[nf], acc[mf][nf], 0, 0, 0);
  }

  // C write: D row = (lane>>4)*4 + q, col = lane&15 (m89-verified layout)
#pragma unroll
  for (int mf = 0; mf < MF; ++mf) {
#pragma unroll
    for (int nf = 0; nf < NF; ++nf) {
      int col = bn + wn + nf * 16 + r;
      if (col < N) {
#pragma unroll
        for (int q = 0; q < 4; ++q) {
          int row = bm + wm + mf * 16 + g * 4 + q;
          C[(size_t)row * N + col] = acc[mf][nf][q];
        }
      }
    }
  }
}

// ---------------------------------------------------------------------------
// Prep: LN(B), LN(C) -> BC; a = A*DT (log-decay), DT -> aDT
// ---------------------------------------------------------------------------
__device__ __forceinline__ float softplusf(float x) {
  return (x > 20.f) ? x : log1pf(expf(x));
}

__device__ __forceinline__ float wave_sum64(float v) {
#pragma unroll
  for (int o = 32; o > 0; o >>= 1) v += __shfl_xor(v, o);
  return v;
}

__global__ __launch_bounds__(64) void prep_kernel(
    const float* __restrict__ proj, const float* __restrict__ dt_bias,
    const float* __restrict__ Bg, const float* __restrict__ Bb,
    const float* __restrict__ Cg, const float* __restrict__ Cb,
    float* __restrict__ BC, float2* __restrict__ aDT) {
  const int r = blockIdx.x;
  const int lane = threadIdx.x;
  const float* p = proj + (size_t)r * D_PROJ;

  float bp = p[2 * D_INNER + lane];
  float cp = p[2 * D_INNER + D_STATE + lane];

  float mb = wave_sum64(bp) * (1.f / 64.f);
  float mc = wave_sum64(cp) * (1.f / 64.f);
  float db = bp - mb, dc = cp - mc;
  float vb = wave_sum64(db * db) * (1.f / 64.f);
  float vc = wave_sum64(dc * dc) * (1.f / 64.f);
  float bn = db * rsqrtf(vb + LN_EPS) * Bg[lane] + Bb[lane];
  float cn = dc * rsqrtf(vc + LN_EPS) * Cg[lane] + Cb[lane];
  BC[(size_t)r * 128 + lane]      = bn;
  BC[(size_t)r * 128 + 64 + lane] = cn;

  if (lane < NHEADS) {
    float ddt = p[2 * D_INNER + 2 * D_STATE + lane];
    float dA  = p[2 * D_INNER + 2 * D_STATE + NHEADS + lane];
    float DT = softplusf(ddt + dt_bias[lane]);
    float Aa = fminf(-softplusf(dA), -A_FLOOR);
    int b = r >> 10;
    int t = r & 1023;
    aDT[((size_t)(b * NHEADS + lane) << 10) + t] = make_float2(Aa * DT, DT);
  }
}

__device__ __forceinline__ float wave_prefix_incl(float v, int lane) {
#pragma unroll
  for (int o = 1; o < 64; o <<= 1) {
    float w = __shfl_up(v, o);
    if (lane >= o) v += w;
  }
  return v;
}

// ---------------------------------------------------------------------------
// chunk_state: T_c[n][p] = sum_s DT_s*exp(csum_end - csum_s) * B_s[n]*x_s[p]
// ---------------------------------------------------------------------------
__global__ __launch_bounds__(256) void chunk_state_kernel(
    const float* __restrict__ proj, const float* __restrict__ BC,
    const float2* __restrict__ aDT, float* __restrict__ Tbuf,
    float* __restrict__ Ebuf) {
  const int blk = blockIdx.x;
  const int c = blk & (NCH - 1), bh = blk >> 4;
  const int b = bh / NHEADS, hh = bh % NHEADS;
  const int tid = threadIdx.x;

  __shared__ float Bs[QC][LDT];
  __shared__ float Xs[QC][LDT];
  __shared__ float coeff[QC];
  __shared__ float etot[1];

  if (tid < 64) {
    float2 ad = aDT[((size_t)bh << 10) + c * QC + tid];
    float cs = wave_prefix_incl(ad.x, tid);
    float tot = __shfl(cs, 63);
    coeff[tid] = ad.y * __expf(tot - cs);
    if (tid == 63) etot[0] = __expf(tot);
  }
  __syncthreads();

  for (int i = tid; i < 1024; i += 256) {
    int s = i >> 4;
    int q = (i & 15) * 4;
    int r = b * SEQ + c * QC + s;
    *(float4*)&Bs[s][q] = *(const float4*)(BC + (size_t)r * 128 + q);
    float4 xv = *(const float4*)(proj + (size_t)r * D_PROJ + D_INNER + hh * 64 + q);
    float cf = coeff[s];
    xv.x *= cf; xv.y *= cf; xv.z *= cf; xv.w *= cf;
    *(float4*)&Xs[s][q] = xv;
  }
  __syncthreads();

  const int ni = (tid & 15) * 4, pi = (tid >> 4) * 4;
  float acc[4][4];
#pragma unroll
  for (int i = 0; i < 4; ++i)
#pragma unroll
    for (int j = 0; j < 4; ++j) acc[i][j] = 0.f;

  for (int s = 0; s < QC; ++s) {
    float bn[4], xp[4];
    *(float4*)bn = *(float4*)&Bs[s][ni];
    *(float4*)xp = *(float4*)&Xs[s][pi];
#pragma unroll
    for (int i = 0; i < 4; ++i)
#pragma unroll
      for (int j = 0; j < 4; ++j)
        acc[i][j] = fmaf(bn[i], xp[j], acc[i][j]);
  }

  float* T = Tbuf + (size_t)blk * 4096;
#pragma unroll
  for (int i = 0; i < 4; ++i)
    *(float4*)(T + (size_t)(ni + i) * 64 + pi) =
        make_float4(acc[i][0], acc[i][1], acc[i][2], acc[i][3]);
  if (tid == 0) Ebuf[blk] = etot[0];
}

// ---------------------------------------------------------------------------
// interchunk: S_in[c+1] = E_c * S_in[c] + T_c
// ---------------------------------------------------------------------------
__global__ __launch_bounds__(256) void interchunk_kernel(
    const float* __restrict__ Tbuf, const float* __restrict__ Ebuf,
    float* __restrict__ Sinbuf) {
  const int bh = blockIdx.x >> 2, part = blockIdx.x & 3;
  const int tid = threadIdx.x;
  const size_t eo = (size_t)part * 1024 + tid * 4;
  float4 s = make_float4(0.f, 0.f, 0.f, 0.f);
#pragma unroll
  for (int c = 0; c < NCH; ++c) {
    size_t off = ((size_t)(bh * NCH + c)) * 4096 + eo;
    *(float4*)(Sinbuf + off) = s;
    float E = Ebuf[bh * NCH + c];
    float4 t4 = *(const float4*)(Tbuf + off);
    s.x = fmaf(E, s.x, t4.x);
    s.y = fmaf(E, s.y, t4.y);
    s.z = fmaf(E, s.z, t4.z);
    s.w = fmaf(E, s.w, t4.w);
  }
}

// ---------------------------------------------------------------------------
// chunk_output: intra+inter chunk Y, + D*x, silu(z) gate -> bf16 Ybuf
// ---------------------------------------------------------------------------
__global__ __launch_bounds__(256) void chunk_output_kernel(
    const float* __restrict__ proj, const float* __restrict__ BC,
    const float2* __restrict__ aDT, const float* __restrict__ Sinbuf,
    const float* __restrict__ Dv, unsigned short* __restrict__ Ybf) {
  const int blk = blockIdx.x;
  const int c = blk & (NCH - 1), bh = blk >> 4;
  const int b = bh / NHEADS, hh = bh % NHEADS;
  const int tid = threadIdx.x;

  __shared__ float smem[3 * 64 * LDT];
  __shared__ float csum[QC];
  __shared__ float DTs[QC];
  float (*CcT)[LDT] = (float(*)[LDT])smem;
  float (*BcT)[LDT] = (float(*)[LDT])(smem + 64 * LDT);
  float (*Sin)[LDT] = (float(*)[LDT])(smem + 2 * 64 * LDT);
  float (*Wb)[LDT]  = CcT;
  float (*Xs)[LDT]  = BcT;

  if (tid < 64) {
    float2 ad = aDT[((size_t)bh << 10) + c * QC + tid];
    csum[tid] = wave_prefix_incl(ad.x, tid);
    DTs[tid] = ad.y;
  }

  const size_t sin_base = (size_t)blk * 4096;
  for (int i = tid; i < 1024; i += 256) {
    int tt = i >> 4;
    int q = (i & 15) * 4;
    int r = b * SEQ + c * QC + tt;
    float4 bv = *(const float4*)(BC + (size_t)r * 128 + q);
    float4 cv = *(const float4*)(BC + (size_t)r * 128 + 64 + q);
    BcT[q + 0][tt] = bv.x; BcT[q + 1][tt] = bv.y;
    BcT[q + 2][tt] = bv.z; BcT[q + 3][tt] = bv.w;
    CcT[q + 0][tt] = cv.x; CcT[q + 1][tt] = cv.y;
    CcT[q + 2][tt] = cv.z; CcT[q + 3][tt] = cv.w;
    *(float4*)&Sin[tt][q] = *(const float4*)(Sinbuf + sin_base + (size_t)tt * 64 + q);
  }
  __syncthreads();

  const int ti = (tid & 15) * 4, si = (tid >> 4) * 4;
  float acc1[4][4], acc2[4][4];
#pragma unroll
  for (int i = 0; i < 4; ++i)
#pragma unroll
    for (int j = 0; j < 4; ++j) { acc1[i][j] = 0.f; acc2[i][j] = 0.f; }

  for (int n = 0; n < 64; ++n) {
    float cv[4], bv[4], sv[4];
    *(float4*)cv = *(float4*)&CcT[n][ti];
    *(float4*)bv = *(float4*)&BcT[n][si];
    *(float4*)sv = *(float4*)&Sin[n][si];
#pragma unroll
    for (int i = 0; i < 4; ++i)
#pragma unroll
      for (int j = 0; j < 4; ++j) {
        acc1[i][j] = fmaf(cv[i], bv[j], acc1[i][j]);
        acc2[i][j] = fmaf(cv[i], sv[j], acc2[i][j]);
      }
  }
  __syncthreads();

#pragma unroll
  for (int j = 0; j < 4; ++j) {
    int s = si + j;
    float dts = DTs[s], cs = csum[s];
    float w4[4];
#pragma unroll
    for (int i = 0; i < 4; ++i) {
      int t = ti + i;
      w4[i] = (s <= t) ? acc1[i][j] * __expf(csum[t] - cs) * dts : 0.f;
    }
    *(float4*)&Wb[s][ti] = *(float4*)w4;
  }
#pragma unroll
  for (int i = 0; i < 4; ++i) {
    float d = __expf(csum[ti + i]);
#pragma unroll
    for (int j = 0; j < 4; ++j) acc2[i][j] *= d;
  }
  for (int i = tid; i < 1024; i += 256) {
    int s = i >> 4;
    int q = (i & 15) * 4;
    int r = b * SEQ + c * QC + s;
    *(float4*)&Xs[s][q] = *(const float4*)(proj + (size_t)r * D_PROJ + D_INNER + hh * 64 + q);
  }
  __syncthreads();

  for (int s = 0; s < 64; ++s) {
    float wv[4], xv[4];
    *(float4*)wv = *(float4*)&Wb[s][ti];
    *(float4*)xv = *(float4*)&Xs[s][si];
#pragma unroll
    for (int i = 0; i < 4; ++i)
#pragma unroll
      for (int j = 0; j < 4; ++j)
        acc2[i][j] = fmaf(wv[i], xv[j], acc2[i][j]);
  }

  const float Dh = Dv[hh];
#pragma unroll
  for (int i = 0; i < 4; ++i) {
    int t = ti + i;
    int r = b * SEQ + c * QC + t;
    float zv[4];
    *(float4*)zv = *(const float4*)(proj + (size_t)r * D_PROJ + hh * 64 + si);
    ushort4 o;
    unsigned short* op = (unsigned short*)&o;
#pragma unroll
    for (int j = 0; j < 4; ++j) {
      float x = Xs[t][si + j];
      float y = acc2[i][j] + Dh * x;
      float z = zv[j];
      op[j] = f2bf(y * (z / (1.f + __expf(-z))));
    }
    *(ushort4*)(Ybf + (size_t)r * D_INNER + hh * 64 + si) = o;
  }
}

// ---------------------------------------------------------------------------
// Launch
// ---------------------------------------------------------------------------
extern "C" void kernel_launch(void* const* d_in, const int* in_sizes, int n_in,
                              void* d_out, int out_size, void* d_ws, size_t ws_size,
                              hipStream_t stream) {
  const float* u       = (const float*)d_in[0];
  const float* Win     = (const float*)d_in[1];
  const float* Wout    = (const float*)d_in[2];
  const float* dt_bias = (const float*)d_in[3];
  const float* Dv      = (const float*)d_in[4];
  const float* Bg      = (const float*)d_in[5];
  const float* Bb      = (const float*)d_in[6];
  const float* Cg      = (const float*)d_in[7];
  const float* Cb      = (const float*)d_in[8];
  float* out = (float*)d_out;

  float* ws = (float*)d_ws;
  float*  proj    = ws;                                   // 2048*3248
  float*  BC      = proj + (size_t)ROWS * D_PROJ;         // 2048*128
  float*  aDTf    = BC + (size_t)ROWS * 128;              // 48*1024*2
  float2* aDT     = (float2*)aDTf;
  float*  Tbuf    = aDTf + (size_t)2 * BATCH * NHEADS * SEQ;        // 768*4096
  float*  Ebuf    = Tbuf + (size_t)BATCH * NHEADS * NCH * 4096;     // 1024
  float*  Sinbuf  = Ebuf + 1024;                          // 768*4096
  float*  Woutbff = Sinbuf + (size_t)BATCH * NHEADS * NCH * 4096;   // 294912 floats

  // bf16 buffers aliased onto dead f32 regions (lifetimes verified):
  unsigned short* ubf    = (unsigned short*)Sinbuf;  // dead before interchunk writes
  unsigned short* Winbf  = (unsigned short*)Tbuf;    // dead before chunk_state writes
  unsigned short* Ybf    = (unsigned short*)Tbuf;    // Tbuf dead after interchunk
  unsigned short* Woutbf = (unsigned short*)Woutbff; // standalone

  // casts (one fused launch)
  cast_all_kernel<<<ROWS + NPAD_WIN + D_MODEL, 256, 0, stream>>>(
      u, Win, Wout, ubf, Winbf, Woutbf);

  // 1) proj = u @ Win.T   (MFMA bf16, 4-buf pipeline, 64x128 tiles)
  dim3 g1(NPAD_WIN / 128, ROWS / 64);    // (26,32) = 832 blocks
  gemm_bt_bf16<64, 128><<<g1, 256, 0, stream>>>(ubf, Winbf, proj, ROWS, D_PROJ, D_MODEL);

  // 2) LN(B), LN(C), a/DT
  prep_kernel<<<ROWS, 64, 0, stream>>>(proj, dt_bias, Bg, Bb, Cg, Cb, BC, aDT);

  // 3) chunked scan
  chunk_state_kernel<<<BATCH * NHEADS * NCH, 256, 0, stream>>>(proj, BC, aDT, Tbuf, Ebuf);
  interchunk_kernel<<<BATCH * NHEADS * 4, 256, 0, stream>>>(Tbuf, Ebuf, Sinbuf);
  chunk_output_kernel<<<BATCH * NHEADS * NCH, 256, 0, stream>>>(proj, BC, aDT, Sinbuf, Dv, Ybf);

  // 4) out = Ybuf @ Wout.T   (MFMA bf16, 4-buf pipeline, 64x64 tiles)
  dim3 g2(D_MODEL / 64, ROWS / 64);      // (12,32) = 384 blocks
  gemm_bt_bf16<64, 64><<<g2, 256, 0, stream>>>(Ybf, Woutbf, out, ROWS, D_MODEL, D_INNER);
}

// Round 7
// 125.265 us; speedup vs baseline: 1.0250x; 1.0250x over previous
//
#include <hip/hip_runtime.h>
#include <cstdint>

#define D_MODEL   768
#define D_STATE   64
#define D_INNER   1536
#define NHEADS    24
#define HEADDIM   64
#define D_PROJ    3248
#define BATCH     2
#define SEQ       1024
#define ROWS      (BATCH*SEQ)   // 2048
#define LN_EPS    1e-5f
#define A_FLOOR   1e-4f
#define QC        64            // chunk length
#define NCH       (SEQ/QC)      // 16
#define LDT       68            // padded LDS stride (floats)
#define NPAD_WIN  3328          // 3248 padded to multiple of 128

typedef __attribute__((ext_vector_type(8))) short short8;
typedef __attribute__((ext_vector_type(4))) float f32x4;

// round-to-nearest-even f32 -> bf16 bits
__device__ __forceinline__ unsigned short f2bf(float f) {
  union { float f; uint32_t u; } v; v.f = f;
  uint32_t r = (v.u + 0x7FFFu + ((v.u >> 16) & 1u)) >> 16;
  return (unsigned short)r;
}

__device__ __forceinline__ void gload_lds16(const void* g, void* l) {
  __builtin_amdgcn_global_load_lds(
      (const __attribute__((address_space(1))) unsigned int*)g,
      (__attribute__((address_space(3))) unsigned int*)l, 16, 0, 0);
}

// counted vmcnt wait (T4) — literal strings, compile-time dispatched
template <int N>
__device__ __forceinline__ void wait_vm() {
  static_assert(N == 0 || N == 2 || N == 3 || N == 4 || N == 6, "unsupported vmcnt");
  if constexpr (N == 0) asm volatile("s_waitcnt vmcnt(0)" ::: "memory");
  else if constexpr (N == 2) asm volatile("s_waitcnt vmcnt(2)" ::: "memory");
  else if constexpr (N == 3) asm volatile("s_waitcnt vmcnt(3)" ::: "memory");
  else if constexpr (N == 4) asm volatile("s_waitcnt vmcnt(4)" ::: "memory");
  else if constexpr (N == 6) asm volatile("s_waitcnt vmcnt(6)" ::: "memory");
}

// ---------------------------------------------------------------------------
// Fused casts: u (2048x768), Win (3248->3328 x768 zero-padded), Wout (768x1536)
// ---------------------------------------------------------------------------
__global__ __launch_bounds__(256) void cast_all_kernel(
    const float* __restrict__ u, const float* __restrict__ Win,
    const float* __restrict__ Wout, unsigned short* __restrict__ ubf,
    unsigned short* __restrict__ Winbf, unsigned short* __restrict__ Woutbf) {
  int b = blockIdx.x;
  const float* src; unsigned short* dst; int cols, srcRows, row;
  if (b < ROWS)                 { row = b;                    src = u;    dst = ubf;    cols = D_MODEL; srcRows = ROWS;   }
  else if (b < ROWS + NPAD_WIN) { row = b - ROWS;             src = Win;  dst = Winbf;  cols = D_MODEL; srcRows = D_PROJ; }
  else                          { row = b - ROWS - NPAD_WIN;  src = Wout; dst = Woutbf; cols = D_INNER; srcRows = D_MODEL;}
  const bool live = row < srcRows;
  for (int c = threadIdx.x * 4; c < cols; c += 256 * 4) {
    float4 v = make_float4(0.f, 0.f, 0.f, 0.f);
    if (live) v = *(const float4*)(src + (size_t)row * cols + c);
    ushort4 o;
    o.x = f2bf(v.x); o.y = f2bf(v.y); o.z = f2bf(v.z); o.w = f2bf(v.w);
    *(ushort4*)(dst + (size_t)row * cols + c) = o;
  }
}

// ---------------------------------------------------------------------------
// MFMA bf16 GEMM (NT), 4-buffer / prefetch-distance-3 / ONE barrier per iter,
// XCD-aware panel swizzle (T1): each XCD owns a CONTIGUOUS chunk of the tile
// grid so its 4MB L2 retains the shared A/B panels.
//   g = (bid&7)*PER + (bid>>3)   (bijective: NWG % 8 == 0, static_asserted)
//   XMAJOR=false (GEMM1): x = g/GY, y = g%GY  -> per-XCD: all-M x few-N-cols
//     (working set = A full 3.1MB + B slice ~0.6MB, fits 4MB L2)
//   XMAJOR=true  (GEMM2): y = g/GX, x = g%GX  -> per-XCD: few-M-rows x all-N
//     (working set = Wout 2.4MB + A panel 0.2MB, fits 4MB L2)
// A (M,K) bf16 rm, B (N,K) bf16 rm, C (M,N) f32. 256 thr = 4 waves (2x2).
// ---------------------------------------------------------------------------
template <int TBM, int TBN, int GX, int GY, bool XMAJOR>
__global__ __launch_bounds__(256) void gemm_bt_bf16(
    const unsigned short* __restrict__ A, const unsigned short* __restrict__ B,
    float* __restrict__ C, int M, int N, int K) {
  constexpr int MF = TBM / 32;
  constexpr int NF = TBN / 32;
  constexpr int NSA = TBM / 16;
  constexpr int NSB = TBN / 16;
  constexpr int LPW = (NSA + NSB) / 4;   // gload_lds per wave per tile (exact)
  static_assert((NSA + NSB) % 4 == 0, "segments must split evenly over waves");
  constexpr int NWG = GX * GY;
  constexpr int PER = NWG / 8;
  static_assert(NWG % 8 == 0, "grid must split evenly over 8 XCDs");
  __shared__ unsigned short Asm[4][TBM * 32];
  __shared__ unsigned short Bsm[4][TBN * 32];

  const int tid = threadIdx.x;
  const int wv = tid >> 6, lane = tid & 63;

  // XCD-chunked bijective swizzle
  const int g = (blockIdx.x & 7) * PER + (blockIdx.x >> 3);
  int bx, by;
  if constexpr (XMAJOR) { by = g / GX; bx = g - by * GX; }
  else                  { bx = g / GY; by = g - bx * GY; }
  const int bm = by * TBM, bn = bx * TBN;

  const int wm = (wv & 1) * (TBM / 2);
  const int wn = (wv >> 1) * (TBN / 2);
  const int gq = lane >> 4, r = lane & 15;

  f32x4 acc[MF][NF];
#pragma unroll
  for (int i = 0; i < MF; ++i)
#pragma unroll
    for (int j = 0; j < NF; ++j) acc[i][j] = (f32x4){0.f, 0.f, 0.f, 0.f};

  auto stage = [&](int k0, int buf) {
    for (int s = wv; s < NSA + NSB; s += 4) {
      if (s < NSA) {
        int chunk = s / (TBM / 64);
        int row0 = (s % (TBM / 64)) * 64;
        gload_lds16(A + (size_t)(bm + row0 + lane) * K + k0 + chunk * 8,
                    (void*)(&Asm[buf][s * 512]));
      } else {
        int s2 = s - NSA;
        int chunk = s2 / (TBN / 64);
        int row0 = (s2 % (TBN / 64)) * 64;
        gload_lds16(B + (size_t)(bn + row0 + lane) * K + k0 + chunk * 8,
                    (void*)(&Bsm[buf][s2 * 512]));
      }
    }
  };

  const int kTiles = K >> 5;   // 24 or 48 here (>= 3)
  stage(0, 0);
  stage(32, 1);
  stage(64, 2);

  for (int t = 0; t < kTiles; ++t) {
    const int cur = t & 3;
    if (t + 2 < kTiles)      wait_vm<2 * LPW>();
    else if (t + 1 < kTiles) wait_vm<LPW>();
    else                     wait_vm<0>();
    __builtin_amdgcn_s_barrier();
    asm volatile("" ::: "memory");   // s_barrier is IntrNoMem: fence reordering

    if (t + 3 < kTiles) stage((t + 3) << 5, (t + 3) & 3);

    short8 a[MF], b[NF];
#pragma unroll
    for (int mf = 0; mf < MF; ++mf)
      a[mf] = *(const short8*)&Asm[cur][gq * TBM * 8 + (wm + mf * 16 + r) * 8];
#pragma unroll
    for (int nf = 0; nf < NF; ++nf)
      b[nf] = *(const short8*)&Bsm[cur][gq * TBN * 8 + (wn + nf * 16 + r) * 8];
#pragma unroll
    for (int mf = 0; mf < MF; ++mf)
#pragma unroll
      for (int nf = 0; nf < NF; ++nf)
        acc[mf][nf] = __builtin_amdgcn_mfma_f32_16x16x32_bf16(a[mf], b[nf], acc[mf][nf], 0, 0, 0);
  }

  // C write: D row = (lane>>4)*4 + q, col = lane&15 (m89-verified layout)
#pragma unroll
  for (int mf = 0; mf < MF; ++mf) {
#pragma unroll
    for (int nf = 0; nf < NF; ++nf) {
      int col = bn + wn + nf * 16 + r;
      if (col < N) {
#pragma unroll
        for (int q = 0; q < 4; ++q) {
          int row = bm + wm + mf * 16 + gq * 4 + q;
          C[(size_t)row * N + col] = acc[mf][nf][q];
        }
      }
    }
  }
}

// ---------------------------------------------------------------------------
// Prep: LN(B), LN(C) -> BC; a = A*DT (log-decay), DT -> aDT
// ---------------------------------------------------------------------------
__device__ __forceinline__ float softplusf(float x) {
  return (x > 20.f) ? x : log1pf(expf(x));
}

__device__ __forceinline__ float wave_sum64(float v) {
#pragma unroll
  for (int o = 32; o > 0; o >>= 1) v += __shfl_xor(v, o);
  return v;
}

__global__ __launch_bounds__(64) void prep_kernel(
    const float* __restrict__ proj, const float* __restrict__ dt_bias,
    const float* __restrict__ Bg, const float* __restrict__ Bb,
    const float* __restrict__ Cg, const float* __restrict__ Cb,
    float* __restrict__ BC, float2* __restrict__ aDT) {
  const int r = blockIdx.x;
  const int lane = threadIdx.x;
  const float* p = proj + (size_t)r * D_PROJ;

  float bp = p[2 * D_INNER + lane];
  float cp = p[2 * D_INNER + D_STATE + lane];

  float mb = wave_sum64(bp) * (1.f / 64.f);
  float mc = wave_sum64(cp) * (1.f / 64.f);
  float db = bp - mb, dc = cp - mc;
  float vb = wave_sum64(db * db) * (1.f / 64.f);
  float vc = wave_sum64(dc * dc) * (1.f / 64.f);
  float bn = db * rsqrtf(vb + LN_EPS) * Bg[lane] + Bb[lane];
  float cn = dc * rsqrtf(vc + LN_EPS) * Cg[lane] + Cb[lane];
  BC[(size_t)r * 128 + lane]      = bn;
  BC[(size_t)r * 128 + 64 + lane] = cn;

  if (lane < NHEADS) {
    float ddt = p[2 * D_INNER + 2 * D_STATE + lane];
    float dA  = p[2 * D_INNER + 2 * D_STATE + NHEADS + lane];
    float DT = softplusf(ddt + dt_bias[lane]);
    float Aa = fminf(-softplusf(dA), -A_FLOOR);
    int b = r >> 10;
    int t = r & 1023;
    aDT[((size_t)(b * NHEADS + lane) << 10) + t] = make_float2(Aa * DT, DT);
  }
}

__device__ __forceinline__ float wave_prefix_incl(float v, int lane) {
#pragma unroll
  for (int o = 1; o < 64; o <<= 1) {
    float w = __shfl_up(v, o);
    if (lane >= o) v += w;
  }
  return v;
}

// ---------------------------------------------------------------------------
// chunk_state: T_c[n][p] = sum_s DT_s*exp(csum_end - csum_s) * B_s[n]*x_s[p]
// ---------------------------------------------------------------------------
__global__ __launch_bounds__(256) void chunk_state_kernel(
    const float* __restrict__ proj, const float* __restrict__ BC,
    const float2* __restrict__ aDT, float* __restrict__ Tbuf,
    float* __restrict__ Ebuf) {
  const int blk = blockIdx.x;
  const int c = blk & (NCH - 1), bh = blk >> 4;
  const int b = bh / NHEADS, hh = bh % NHEADS;
  const int tid = threadIdx.x;

  __shared__ float Bs[QC][LDT];
  __shared__ float Xs[QC][LDT];
  __shared__ float coeff[QC];
  __shared__ float etot[1];

  if (tid < 64) {
    float2 ad = aDT[((size_t)bh << 10) + c * QC + tid];
    float cs = wave_prefix_incl(ad.x, tid);
    float tot = __shfl(cs, 63);
    coeff[tid] = ad.y * __expf(tot - cs);
    if (tid == 63) etot[0] = __expf(tot);
  }
  __syncthreads();

  for (int i = tid; i < 1024; i += 256) {
    int s = i >> 4;
    int q = (i & 15) * 4;
    int r = b * SEQ + c * QC + s;
    *(float4*)&Bs[s][q] = *(const float4*)(BC + (size_t)r * 128 + q);
    float4 xv = *(const float4*)(proj + (size_t)r * D_PROJ + D_INNER + hh * 64 + q);
    float cf = coeff[s];
    xv.x *= cf; xv.y *= cf; xv.z *= cf; xv.w *= cf;
    *(float4*)&Xs[s][q] = xv;
  }
  __syncthreads();

  const int ni = (tid & 15) * 4, pi = (tid >> 4) * 4;
  float acc[4][4];
#pragma unroll
  for (int i = 0; i < 4; ++i)
#pragma unroll
    for (int j = 0; j < 4; ++j) acc[i][j] = 0.f;

  for (int s = 0; s < QC; ++s) {
    float bn[4], xp[4];
    *(float4*)bn = *(float4*)&Bs[s][ni];
    *(float4*)xp = *(float4*)&Xs[s][pi];
#pragma unroll
    for (int i = 0; i < 4; ++i)
#pragma unroll
      for (int j = 0; j < 4; ++j)
        acc[i][j] = fmaf(bn[i], xp[j], acc[i][j]);
  }

  float* T = Tbuf + (size_t)blk * 4096;
#pragma unroll
  for (int i = 0; i < 4; ++i)
    *(float4*)(T + (size_t)(ni + i) * 64 + pi) =
        make_float4(acc[i][0], acc[i][1], acc[i][2], acc[i][3]);
  if (tid == 0) Ebuf[blk] = etot[0];
}

// ---------------------------------------------------------------------------
// interchunk: S_in[c+1] = E_c * S_in[c] + T_c
// ---------------------------------------------------------------------------
__global__ __launch_bounds__(256) void interchunk_kernel(
    const float* __restrict__ Tbuf, const float* __restrict__ Ebuf,
    float* __restrict__ Sinbuf) {
  const int bh = blockIdx.x >> 2, part = blockIdx.x & 3;
  const int tid = threadIdx.x;
  const size_t eo = (size_t)part * 1024 + tid * 4;
  float4 s = make_float4(0.f, 0.f, 0.f, 0.f);
#pragma unroll
  for (int c = 0; c < NCH; ++c) {
    size_t off = ((size_t)(bh * NCH + c)) * 4096 + eo;
    *(float4*)(Sinbuf + off) = s;
    float E = Ebuf[bh * NCH + c];
    float4 t4 = *(const float4*)(Tbuf + off);
    s.x = fmaf(E, s.x, t4.x);
    s.y = fmaf(E, s.y, t4.y);
    s.z = fmaf(E, s.z, t4.z);
    s.w = fmaf(E, s.w, t4.w);
  }
}

// ---------------------------------------------------------------------------
// chunk_output: intra+inter chunk Y, + D*x, silu(z) gate -> bf16 Ybuf
// ---------------------------------------------------------------------------
__global__ __launch_bounds__(256) void chunk_output_kernel(
    const float* __restrict__ proj, const float* __restrict__ BC,
    const float2* __restrict__ aDT, const float* __restrict__ Sinbuf,
    const float* __restrict__ Dv, unsigned short* __restrict__ Ybf) {
  const int blk = blockIdx.x;
  const int c = blk & (NCH - 1), bh = blk >> 4;
  const int b = bh / NHEADS, hh = bh % NHEADS;
  const int tid = threadIdx.x;

  __shared__ float smem[3 * 64 * LDT];
  __shared__ float csum[QC];
  __shared__ float DTs[QC];
  float (*CcT)[LDT] = (float(*)[LDT])smem;
  float (*BcT)[LDT] = (float(*)[LDT])(smem + 64 * LDT);
  float (*Sin)[LDT] = (float(*)[LDT])(smem + 2 * 64 * LDT);
  float (*Wb)[LDT]  = CcT;
  float (*Xs)[LDT]  = BcT;

  if (tid < 64) {
    float2 ad = aDT[((size_t)bh << 10) + c * QC + tid];
    csum[tid] = wave_prefix_incl(ad.x, tid);
    DTs[tid] = ad.y;
  }

  const size_t sin_base = (size_t)blk * 4096;
  for (int i = tid; i < 1024; i += 256) {
    int tt = i >> 4;
    int q = (i & 15) * 4;
    int r = b * SEQ + c * QC + tt;
    float4 bv = *(const float4*)(BC + (size_t)r * 128 + q);
    float4 cv = *(const float4*)(BC + (size_t)r * 128 + 64 + q);
    BcT[q + 0][tt] = bv.x; BcT[q + 1][tt] = bv.y;
    BcT[q + 2][tt] = bv.z; BcT[q + 3][tt] = bv.w;
    CcT[q + 0][tt] = cv.x; CcT[q + 1][tt] = cv.y;
    CcT[q + 2][tt] = cv.z; CcT[q + 3][tt] = cv.w;
    *(float4*)&Sin[tt][q] = *(const float4*)(Sinbuf + sin_base + (size_t)tt * 64 + q);
  }
  __syncthreads();

  const int ti = (tid & 15) * 4, si = (tid >> 4) * 4;
  float acc1[4][4], acc2[4][4];
#pragma unroll
  for (int i = 0; i < 4; ++i)
#pragma unroll
    for (int j = 0; j < 4; ++j) { acc1[i][j] = 0.f; acc2[i][j] = 0.f; }

  for (int n = 0; n < 64; ++n) {
    float cv[4], bv[4], sv[4];
    *(float4*)cv = *(float4*)&CcT[n][ti];
    *(float4*)bv = *(float4*)&BcT[n][si];
    *(float4*)sv = *(float4*)&Sin[n][si];
#pragma unroll
    for (int i = 0; i < 4; ++i)
#pragma unroll
      for (int j = 0; j < 4; ++j) {
        acc1[i][j] = fmaf(cv[i], bv[j], acc1[i][j]);
        acc2[i][j] = fmaf(cv[i], sv[j], acc2[i][j]);
      }
  }
  __syncthreads();

#pragma unroll
  for (int j = 0; j < 4; ++j) {
    int s = si + j;
    float dts = DTs[s], cs = csum[s];
    float w4[4];
#pragma unroll
    for (int i = 0; i < 4; ++i) {
      int t = ti + i;
      w4[i] = (s <= t) ? acc1[i][j] * __expf(csum[t] - cs) * dts : 0.f;
    }
    *(float4*)&Wb[s][ti] = *(float4*)w4;
  }
#pragma unroll
  for (int i = 0; i < 4; ++i) {
    float d = __expf(csum[ti + i]);
#pragma unroll
    for (int j = 0; j < 4; ++j) acc2[i][j] *= d;
  }
  for (int i = tid; i < 1024; i += 256) {
    int s = i >> 4;
    int q = (i & 15) * 4;
    int r = b * SEQ + c * QC + s;
    *(float4*)&Xs[s][q] = *(const float4*)(proj + (size_t)r * D_PROJ + D_INNER + hh * 64 + q);
  }
  __syncthreads();

  for (int s = 0; s < 64; ++s) {
    float wv[4], xv[4];
    *(float4*)wv = *(float4*)&Wb[s][ti];
    *(float4*)xv = *(float4*)&Xs[s][si];
#pragma unroll
    for (int i = 0; i < 4; ++i)
#pragma unroll
      for (int j = 0; j < 4; ++j)
        acc2[i][j] = fmaf(wv[i], xv[j], acc2[i][j]);
  }

  const float Dh = Dv[hh];
#pragma unroll
  for (int i = 0; i < 4; ++i) {
    int t = ti + i;
    int r = b * SEQ + c * QC + t;
    float zv[4];
    *(float4*)zv = *(const float4*)(proj + (size_t)r * D_PROJ + hh * 64 + si);
    ushort4 o;
    unsigned short* op = (unsigned short*)&o;
#pragma unroll
    for (int j = 0; j < 4; ++j) {
      float x = Xs[t][si + j];
      float y = acc2[i][j] + Dh * x;
      float z = zv[j];
      op[j] = f2bf(y * (z / (1.f + __expf(-z))));
    }
    *(ushort4*)(Ybf + (size_t)r * D_INNER + hh * 64 + si) = o;
  }
}

// ---------------------------------------------------------------------------
// Launch
// ---------------------------------------------------------------------------
extern "C" void kernel_launch(void* const* d_in, const int* in_sizes, int n_in,
                              void* d_out, int out_size, void* d_ws, size_t ws_size,
                              hipStream_t stream) {
  const float* u       = (const float*)d_in[0];
  const float* Win     = (const float*)d_in[1];
  const float* Wout    = (const float*)d_in[2];
  const float* dt_bias = (const float*)d_in[3];
  const float* Dv      = (const float*)d_in[4];
  const float* Bg      = (const float*)d_in[5];
  const float* Bb      = (const float*)d_in[6];
  const float* Cg      = (const float*)d_in[7];
  const float* Cb      = (const float*)d_in[8];
  float* out = (float*)d_out;

  float* ws = (float*)d_ws;
  float*  proj    = ws;                                   // 2048*3248
  float*  BC      = proj + (size_t)ROWS * D_PROJ;         // 2048*128
  float*  aDTf    = BC + (size_t)ROWS * 128;              // 48*1024*2
  float2* aDT     = (float2*)aDTf;
  float*  Tbuf    = aDTf + (size_t)2 * BATCH * NHEADS * SEQ;        // 768*4096
  float*  Ebuf    = Tbuf + (size_t)BATCH * NHEADS * NCH * 4096;     // 1024
  float*  Sinbuf  = Ebuf + 1024;                          // 768*4096
  float*  Woutbff = Sinbuf + (size_t)BATCH * NHEADS * NCH * 4096;   // 294912 floats

  // bf16 buffers aliased onto dead f32 regions (lifetimes verified):
  unsigned short* ubf    = (unsigned short*)Sinbuf;  // dead before interchunk writes
  unsigned short* Winbf  = (unsigned short*)Tbuf;    // dead before chunk_state writes
  unsigned short* Ybf    = (unsigned short*)Tbuf;    // Tbuf dead after interchunk
  unsigned short* Woutbf = (unsigned short*)Woutbff; // standalone

  // casts (one fused launch)
  cast_all_kernel<<<ROWS + NPAD_WIN + D_MODEL, 256, 0, stream>>>(
      u, Win, Wout, ubf, Winbf, Woutbf);

  // 1) proj = u @ Win.T   (MFMA bf16, 4-buf pipeline, XCD panel swizzle)
  //    grid: 26 x-tiles * 32 y-tiles = 832 blocks, y-fastest within XCD chunk
  gemm_bt_bf16<64, 128, 26, 32, false><<<832, 256, 0, stream>>>(
      ubf, Winbf, proj, ROWS, D_PROJ, D_MODEL);

  // 2) LN(B), LN(C), a/DT
  prep_kernel<<<ROWS, 64, 0, stream>>>(proj, dt_bias, Bg, Bb, Cg, Cb, BC, aDT);

  // 3) chunked scan
  chunk_state_kernel<<<BATCH * NHEADS * NCH, 256, 0, stream>>>(proj, BC, aDT, Tbuf, Ebuf);
  interchunk_kernel<<<BATCH * NHEADS * 4, 256, 0, stream>>>(Tbuf, Ebuf, Sinbuf);
  chunk_output_kernel<<<BATCH * NHEADS * NCH, 256, 0, stream>>>(proj, BC, aDT, Sinbuf, Dv, Ybf);

  // 4) out = Ybuf @ Wout.T   (MFMA bf16, 4-buf pipeline, XCD panel swizzle)
  //    grid: 12 x-tiles * 32 y-tiles = 384 blocks, x-fastest within XCD chunk
  gemm_bt_bf16<64, 64, 12, 32, true><<<384, 256, 0, stream>>>(
      Ybf, Woutbf, out, ROWS, D_MODEL, D_INNER);
}

// Round 8
// 106.683 us; speedup vs baseline: 1.2035x; 1.1742x over previous
//
#include <hip/hip_runtime.h>
#include <cstdint>

#define D_MODEL   768
#define D_STATE   64
#define D_INNER   1536
#define NHEADS    24
#define HEADDIM   64
#define D_PROJ    3248
#define BATCH     2
#define SEQ       1024
#define ROWS      (BATCH*SEQ)   // 2048
#define LN_EPS    1e-5f
#define A_FLOOR   1e-4f
#define QC        64            // chunk length
#define NCH       (SEQ/QC)      // 16
#define LDT       68            // padded LDS stride (floats)

// packed-operand geometry: [kt][rg][c4][64 rows][8 bf16] (4KB per (kt,rg))
#define RG_U    32   // 2048/64 rowgroups (u and Ybuf)
#define RG_WIN  52   // 3328/64 (Win padded 3248->3328)
#define RG_WO   12   // 768/64  (Wout)
#define KT_1    24   // K=768/32
#define KT_2    48   // K=1536/32

typedef __attribute__((ext_vector_type(8))) short short8;
typedef __attribute__((ext_vector_type(4))) float f32x4;

// round-to-nearest-even f32 -> bf16 bits
__device__ __forceinline__ unsigned short f2bf(float f) {
  union { float f; uint32_t u; } v; v.f = f;
  uint32_t r = (v.u + 0x7FFFu + ((v.u >> 16) & 1u)) >> 16;
  return (unsigned short)r;
}

__device__ __forceinline__ void gload_lds16(const void* g, void* l) {
  __builtin_amdgcn_global_load_lds(
      (const __attribute__((address_space(1))) unsigned int*)g,
      (__attribute__((address_space(3))) unsigned int*)l, 16, 0, 0);
}

// counted vmcnt wait (T4)
template <int N>
__device__ __forceinline__ void wait_vm() {
  static_assert(N == 0 || N == 2 || N == 3 || N == 4 || N == 6, "unsupported vmcnt");
  if constexpr (N == 0) asm volatile("s_waitcnt vmcnt(0)" ::: "memory");
  else if constexpr (N == 2) asm volatile("s_waitcnt vmcnt(2)" ::: "memory");
  else if constexpr (N == 3) asm volatile("s_waitcnt vmcnt(3)" ::: "memory");
  else if constexpr (N == 4) asm volatile("s_waitcnt vmcnt(4)" ::: "memory");
  else if constexpr (N == 6) asm volatile("s_waitcnt vmcnt(6)" ::: "memory");
}

// ---------------------------------------------------------------------------
// Pack f32 row-major -> bf16 [kt][rg][c][64][8]. One block per (matrix,kt,rg);
// thread t: lr=t>>2 (row in group), cq=t&3 (8-elem chunk). Reads 32B coalesced
// per row; writes 16B at c*1024+lr*16 — contiguous 256B runs per wave.
// ---------------------------------------------------------------------------
__global__ __launch_bounds__(256) void pack_all_kernel(
    const float* __restrict__ u, const float* __restrict__ Win,
    const float* __restrict__ Wout, unsigned short* __restrict__ upk,
    unsigned short* __restrict__ Winpk, unsigned short* __restrict__ Wopk) {
  int b = blockIdx.x;
  const float* src; unsigned short* dst; int K, RG, kt, rg, srcRows;
  if (b < KT_1 * RG_U) {
    src = u; dst = upk; K = 768; RG = RG_U; kt = b / RG_U; rg = b % RG_U; srcRows = ROWS;
  } else if (b < KT_1 * RG_U + KT_1 * RG_WIN) {
    int i = b - KT_1 * RG_U;
    src = Win; dst = Winpk; K = 768; RG = RG_WIN; kt = i / RG_WIN; rg = i % RG_WIN; srcRows = D_PROJ;
  } else {
    int i = b - KT_1 * RG_U - KT_1 * RG_WIN;
    src = Wout; dst = Wopk; K = 1536; RG = RG_WO; kt = i / RG_WO; rg = i % RG_WO; srcRows = D_MODEL;
  }
  const int t = threadIdx.x;
  const int lr = t >> 2, cq = t & 3;
  const int R = rg * 64 + lr;
  float4 v0 = make_float4(0.f, 0.f, 0.f, 0.f), v1 = v0;
  if (R < srcRows) {
    const float* p = src + (size_t)R * K + kt * 32 + cq * 8;
    v0 = *(const float4*)p;
    v1 = *(const float4*)(p + 4);
  }
  ushort4 oa, ob;
  oa.x = f2bf(v0.x); oa.y = f2bf(v0.y); oa.z = f2bf(v0.z); oa.w = f2bf(v0.w);
  ob.x = f2bf(v1.x); ob.y = f2bf(v1.y); ob.z = f2bf(v1.z); ob.w = f2bf(v1.w);
  unsigned short* o = dst + ((size_t)(kt * RG + rg) * 4 + cq) * 512 + lr * 8;
  *(ushort4*)o = oa;
  *(ushort4*)(o + 4) = ob;
}

// ---------------------------------------------------------------------------
// MFMA bf16 GEMM (NT) on PACKED operands. 4-buf / prefetch-3 / 1 barrier/iter,
// XCD panel swizzle. Each staging segment is a CONTIGUOUS 1KB global read
// (lane l reads src+l*16B) -> 8-16 cache lines/instr instead of 64.
// LDS image per rowgroup: [c4][64][8] (row stride 16B -> 2-way-free ds_read).
// aRG/bRG: rowgroups per k-panel in the packed operands.
// ---------------------------------------------------------------------------
template <int TBM, int TBN, int GX, int GY, bool XMAJOR>
__global__ __launch_bounds__(256) void gemm_bt_bf16(
    const unsigned short* __restrict__ A, const unsigned short* __restrict__ B,
    float* __restrict__ C, int aRG, int bRG, int M, int N, int K) {
  constexpr int MF = TBM / 32;
  constexpr int NF = TBN / 32;
  constexpr int NSA = TBM / 16;
  constexpr int NSB = TBN / 16;
  constexpr int LPW = (NSA + NSB) / 4;
  static_assert((NSA + NSB) % 4 == 0, "segments must split evenly over waves");
  constexpr int NWG = GX * GY;
  constexpr int PER = NWG / 8;
  static_assert(NWG % 8 == 0, "grid must split evenly over 8 XCDs");
  __shared__ unsigned short Asm[4][TBM * 32];
  __shared__ unsigned short Bsm[4][TBN * 32];

  const int tid = threadIdx.x;
  const int wv = tid >> 6, lane = tid & 63;

  // XCD-chunked bijective swizzle
  const int g = (blockIdx.x & 7) * PER + (blockIdx.x >> 3);
  int bx, by;
  if constexpr (XMAJOR) { by = g / GX; bx = g - by * GX; }
  else                  { bx = g / GY; by = g - bx * GY; }
  const int bm = by * TBM, bn = bx * TBN;

  const int wm = (wv & 1) * (TBM / 2);
  const int wn = (wv >> 1) * (TBN / 2);
  const int gq = lane >> 4, r = lane & 15;

  f32x4 acc[MF][NF];
#pragma unroll
  for (int i = 0; i < MF; ++i)
#pragma unroll
    for (int j = 0; j < NF; ++j) acc[i][j] = (f32x4){0.f, 0.f, 0.f, 0.f};

  auto stage = [&](int kt, int buf) {
    for (int s = wv; s < NSA + NSB; s += 4) {
      if (s < NSA) {
        const unsigned short* src =
            A + ((size_t)kt * aRG + (bm >> 6) + (s >> 2)) * 2048 + (s & 3) * 512 + lane * 8;
        gload_lds16(src, (void*)(&Asm[buf][s * 512]));
      } else {
        int s2 = s - NSA;
        const unsigned short* src =
            B + ((size_t)kt * bRG + (bn >> 6) + (s2 >> 2)) * 2048 + (s2 & 3) * 512 + lane * 8;
        gload_lds16(src, (void*)(&Bsm[buf][s2 * 512]));
      }
    }
  };

  const int kTiles = K >> 5;
  stage(0, 0);
  stage(1, 1);
  stage(2, 2);

  for (int t = 0; t < kTiles; ++t) {
    const int cur = t & 3;
    if (t + 2 < kTiles)      wait_vm<2 * LPW>();
    else if (t + 1 < kTiles) wait_vm<LPW>();
    else                     wait_vm<0>();
    __builtin_amdgcn_s_barrier();
    asm volatile("" ::: "memory");

    if (t + 3 < kTiles) stage(t + 3, (t + 3) & 3);

    short8 a[MF], b[NF];
#pragma unroll
    for (int mf = 0; mf < MF; ++mf) {
      int ra = wm + mf * 16 + r;
      a[mf] = *(const short8*)&Asm[cur][(ra >> 6) * 2048 + gq * 512 + (ra & 63) * 8];
    }
#pragma unroll
    for (int nf = 0; nf < NF; ++nf) {
      int rb = wn + nf * 16 + r;
      b[nf] = *(const short8*)&Bsm[cur][(rb >> 6) * 2048 + gq * 512 + (rb & 63) * 8];
    }
#pragma unroll
    for (int mf = 0; mf < MF; ++mf)
#pragma unroll
      for (int nf = 0; nf < NF; ++nf)
        acc[mf][nf] = __builtin_amdgcn_mfma_f32_16x16x32_bf16(a[mf], b[nf], acc[mf][nf], 0, 0, 0);
  }

  // C write: D row = (lane>>4)*4 + q, col = lane&15 (m89-verified layout)
#pragma unroll
  for (int mf = 0; mf < MF; ++mf) {
#pragma unroll
    for (int nf = 0; nf < NF; ++nf) {
      int col = bn + wn + nf * 16 + r;
      if (col < N) {
#pragma unroll
        for (int q = 0; q < 4; ++q) {
          int row = bm + wm + mf * 16 + gq * 4 + q;
          C[(size_t)row * N + col] = acc[mf][nf][q];
        }
      }
    }
  }
}

// ---------------------------------------------------------------------------
// Prep: LN(B), LN(C) -> BC; a = A*DT (log-decay), DT -> aDT
// ---------------------------------------------------------------------------
__device__ __forceinline__ float softplusf(float x) {
  return (x > 20.f) ? x : log1pf(expf(x));
}

__device__ __forceinline__ float wave_sum64(float v) {
#pragma unroll
  for (int o = 32; o > 0; o >>= 1) v += __shfl_xor(v, o);
  return v;
}

__global__ __launch_bounds__(64) void prep_kernel(
    const float* __restrict__ proj, const float* __restrict__ dt_bias,
    const float* __restrict__ Bg, const float* __restrict__ Bb,
    const float* __restrict__ Cg, const float* __restrict__ Cb,
    float* __restrict__ BC, float2* __restrict__ aDT) {
  const int r = blockIdx.x;
  const int lane = threadIdx.x;
  const float* p = proj + (size_t)r * D_PROJ;

  float bp = p[2 * D_INNER + lane];
  float cp = p[2 * D_INNER + D_STATE + lane];

  float mb = wave_sum64(bp) * (1.f / 64.f);
  float mc = wave_sum64(cp) * (1.f / 64.f);
  float db = bp - mb, dc = cp - mc;
  float vb = wave_sum64(db * db) * (1.f / 64.f);
  float vc = wave_sum64(dc * dc) * (1.f / 64.f);
  float bn = db * rsqrtf(vb + LN_EPS) * Bg[lane] + Bb[lane];
  float cn = dc * rsqrtf(vc + LN_EPS) * Cg[lane] + Cb[lane];
  BC[(size_t)r * 128 + lane]      = bn;
  BC[(size_t)r * 128 + 64 + lane] = cn;

  if (lane < NHEADS) {
    float ddt = p[2 * D_INNER + 2 * D_STATE + lane];
    float dA  = p[2 * D_INNER + 2 * D_STATE + NHEADS + lane];
    float DT = softplusf(ddt + dt_bias[lane]);
    float Aa = fminf(-softplusf(dA), -A_FLOOR);
    int b = r >> 10;
    int t = r & 1023;
    aDT[((size_t)(b * NHEADS + lane) << 10) + t] = make_float2(Aa * DT, DT);
  }
}

__device__ __forceinline__ float wave_prefix_incl(float v, int lane) {
#pragma unroll
  for (int o = 1; o < 64; o <<= 1) {
    float w = __shfl_up(v, o);
    if (lane >= o) v += w;
  }
  return v;
}

// ---------------------------------------------------------------------------
// chunk_state: T_c[n][p] = sum_s DT_s*exp(csum_end - csum_s) * B_s[n]*x_s[p]
// ---------------------------------------------------------------------------
__global__ __launch_bounds__(256) void chunk_state_kernel(
    const float* __restrict__ proj, const float* __restrict__ BC,
    const float2* __restrict__ aDT, float* __restrict__ Tbuf,
    float* __restrict__ Ebuf) {
  const int blk = blockIdx.x;
  const int c = blk & (NCH - 1), bh = blk >> 4;
  const int b = bh / NHEADS, hh = bh % NHEADS;
  const int tid = threadIdx.x;

  __shared__ float Bs[QC][LDT];
  __shared__ float Xs[QC][LDT];
  __shared__ float coeff[QC];
  __shared__ float etot[1];

  if (tid < 64) {
    float2 ad = aDT[((size_t)bh << 10) + c * QC + tid];
    float cs = wave_prefix_incl(ad.x, tid);
    float tot = __shfl(cs, 63);
    coeff[tid] = ad.y * __expf(tot - cs);
    if (tid == 63) etot[0] = __expf(tot);
  }
  __syncthreads();

  for (int i = tid; i < 1024; i += 256) {
    int s = i >> 4;
    int q = (i & 15) * 4;
    int r = b * SEQ + c * QC + s;
    *(float4*)&Bs[s][q] = *(const float4*)(BC + (size_t)r * 128 + q);
    float4 xv = *(const float4*)(proj + (size_t)r * D_PROJ + D_INNER + hh * 64 + q);
    float cf = coeff[s];
    xv.x *= cf; xv.y *= cf; xv.z *= cf; xv.w *= cf;
    *(float4*)&Xs[s][q] = xv;
  }
  __syncthreads();

  const int ni = (tid & 15) * 4, pi = (tid >> 4) * 4;
  float acc[4][4];
#pragma unroll
  for (int i = 0; i < 4; ++i)
#pragma unroll
    for (int j = 0; j < 4; ++j) acc[i][j] = 0.f;

  for (int s = 0; s < QC; ++s) {
    float bn[4], xp[4];
    *(float4*)bn = *(float4*)&Bs[s][ni];
    *(float4*)xp = *(float4*)&Xs[s][pi];
#pragma unroll
    for (int i = 0; i < 4; ++i)
#pragma unroll
      for (int j = 0; j < 4; ++j)
        acc[i][j] = fmaf(bn[i], xp[j], acc[i][j]);
  }

  float* T = Tbuf + (size_t)blk * 4096;
#pragma unroll
  for (int i = 0; i < 4; ++i)
    *(float4*)(T + (size_t)(ni + i) * 64 + pi) =
        make_float4(acc[i][0], acc[i][1], acc[i][2], acc[i][3]);
  if (tid == 0) Ebuf[blk] = etot[0];
}

// ---------------------------------------------------------------------------
// interchunk: S_in[c+1] = E_c * S_in[c] + T_c
// ---------------------------------------------------------------------------
__global__ __launch_bounds__(256) void interchunk_kernel(
    const float* __restrict__ Tbuf, const float* __restrict__ Ebuf,
    float* __restrict__ Sinbuf) {
  const int bh = blockIdx.x >> 2, part = blockIdx.x & 3;
  const int tid = threadIdx.x;
  const size_t eo = (size_t)part * 1024 + tid * 4;
  float4 s = make_float4(0.f, 0.f, 0.f, 0.f);
#pragma unroll
  for (int c = 0; c < NCH; ++c) {
    size_t off = ((size_t)(bh * NCH + c)) * 4096 + eo;
    *(float4*)(Sinbuf + off) = s;
    float E = Ebuf[bh * NCH + c];
    float4 t4 = *(const float4*)(Tbuf + off);
    s.x = fmaf(E, s.x, t4.x);
    s.y = fmaf(E, s.y, t4.y);
    s.z = fmaf(E, s.z, t4.z);
    s.w = fmaf(E, s.w, t4.w);
  }
}

// ---------------------------------------------------------------------------
// chunk_output: intra+inter chunk Y, + D*x, silu(z) gate -> PACKED bf16 Ybuf
// ---------------------------------------------------------------------------
__global__ __launch_bounds__(256) void chunk_output_kernel(
    const float* __restrict__ proj, const float* __restrict__ BC,
    const float2* __restrict__ aDT, const float* __restrict__ Sinbuf,
    const float* __restrict__ Dv, unsigned short* __restrict__ Ybf) {
  const int blk = blockIdx.x;
  const int c = blk & (NCH - 1), bh = blk >> 4;
  const int b = bh / NHEADS, hh = bh % NHEADS;
  const int tid = threadIdx.x;

  __shared__ float smem[3 * 64 * LDT];
  __shared__ float csum[QC];
  __shared__ float DTs[QC];
  float (*CcT)[LDT] = (float(*)[LDT])smem;
  float (*BcT)[LDT] = (float(*)[LDT])(smem + 64 * LDT);
  float (*Sin)[LDT] = (float(*)[LDT])(smem + 2 * 64 * LDT);
  float (*Wb)[LDT]  = CcT;
  float (*Xs)[LDT]  = BcT;

  if (tid < 64) {
    float2 ad = aDT[((size_t)bh << 10) + c * QC + tid];
    csum[tid] = wave_prefix_incl(ad.x, tid);
    DTs[tid] = ad.y;
  }

  const size_t sin_base = (size_t)blk * 4096;
  for (int i = tid; i < 1024; i += 256) {
    int tt = i >> 4;
    int q = (i & 15) * 4;
    int r = b * SEQ + c * QC + tt;
    float4 bv = *(const float4*)(BC + (size_t)r * 128 + q);
    float4 cv = *(const float4*)(BC + (size_t)r * 128 + 64 + q);
    BcT[q + 0][tt] = bv.x; BcT[q + 1][tt] = bv.y;
    BcT[q + 2][tt] = bv.z; BcT[q + 3][tt] = bv.w;
    CcT[q + 0][tt] = cv.x; CcT[q + 1][tt] = cv.y;
    CcT[q + 2][tt] = cv.z; CcT[q + 3][tt] = cv.w;
    *(float4*)&Sin[tt][q] = *(const float4*)(Sinbuf + sin_base + (size_t)tt * 64 + q);
  }
  __syncthreads();

  const int ti = (tid & 15) * 4, si = (tid >> 4) * 4;
  float acc1[4][4], acc2[4][4];
#pragma unroll
  for (int i = 0; i < 4; ++i)
#pragma unroll
    for (int j = 0; j < 4; ++j) { acc1[i][j] = 0.f; acc2[i][j] = 0.f; }

  for (int n = 0; n < 64; ++n) {
    float cv[4], bv[4], sv[4];
    *(float4*)cv = *(float4*)&CcT[n][ti];
    *(float4*)bv = *(float4*)&BcT[n][si];
    *(float4*)sv = *(float4*)&Sin[n][si];
#pragma unroll
    for (int i = 0; i < 4; ++i)
#pragma unroll
      for (int j = 0; j < 4; ++j) {
        acc1[i][j] = fmaf(cv[i], bv[j], acc1[i][j]);
        acc2[i][j] = fmaf(cv[i], sv[j], acc2[i][j]);
      }
  }
  __syncthreads();

#pragma unroll
  for (int j = 0; j < 4; ++j) {
    int s = si + j;
    float dts = DTs[s], cs = csum[s];
    float w4[4];
#pragma unroll
    for (int i = 0; i < 4; ++i) {
      int t = ti + i;
      w4[i] = (s <= t) ? acc1[i][j] * __expf(csum[t] - cs) * dts : 0.f;
    }
    *(float4*)&Wb[s][ti] = *(float4*)w4;
  }
#pragma unroll
  for (int i = 0; i < 4; ++i) {
    float d = __expf(csum[ti + i]);
#pragma unroll
    for (int j = 0; j < 4; ++j) acc2[i][j] *= d;
  }
  for (int i = tid; i < 1024; i += 256) {
    int s = i >> 4;
    int q = (i & 15) * 4;
    int r = b * SEQ + c * QC + s;
    *(float4*)&Xs[s][q] = *(const float4*)(proj + (size_t)r * D_PROJ + D_INNER + hh * 64 + q);
  }
  __syncthreads();

  for (int s = 0; s < 64; ++s) {
    float wv[4], xv[4];
    *(float4*)wv = *(float4*)&Wb[s][ti];
    *(float4*)xv = *(float4*)&Xs[s][si];
#pragma unroll
    for (int i = 0; i < 4; ++i)
#pragma unroll
      for (int j = 0; j < 4; ++j)
        acc2[i][j] = fmaf(wv[i], xv[j], acc2[i][j]);
  }

  // epilogue -> packed Ybf: kt = col/32, cseg = (col%32)/8, rg = r/64, lr=r%64
  const float Dh = Dv[hh];
  const int kt = hh * 2 + (si >> 5);
  const int cseg = (si >> 3) & 3;
  const int j0 = si & 7;          // 0 or 4
  const int rg = b * 16 + c;      // r/64 for rows of this chunk
#pragma unroll
  for (int i = 0; i < 4; ++i) {
    int t = ti + i;
    int r = b * SEQ + c * QC + t;
    float zv[4];
    *(float4*)zv = *(const float4*)(proj + (size_t)r * D_PROJ + hh * 64 + si);
    ushort4 o;
    unsigned short* op = (unsigned short*)&o;
#pragma unroll
    for (int j = 0; j < 4; ++j) {
      float x = Xs[t][si + j];
      float y = acc2[i][j] + Dh * x;
      float z = zv[j];
      op[j] = f2bf(y * (z / (1.f + __expf(-z))));
    }
    *(ushort4*)(Ybf + ((size_t)(kt * RG_U + rg) * 4 + cseg) * 512 + t * 8 + j0) = o;
  }
}

// ---------------------------------------------------------------------------
// Launch
// ---------------------------------------------------------------------------
extern "C" void kernel_launch(void* const* d_in, const int* in_sizes, int n_in,
                              void* d_out, int out_size, void* d_ws, size_t ws_size,
                              hipStream_t stream) {
  const float* u       = (const float*)d_in[0];
  const float* Win     = (const float*)d_in[1];
  const float* Wout    = (const float*)d_in[2];
  const float* dt_bias = (const float*)d_in[3];
  const float* Dv      = (const float*)d_in[4];
  const float* Bg      = (const float*)d_in[5];
  const float* Bb      = (const float*)d_in[6];
  const float* Cg      = (const float*)d_in[7];
  const float* Cb      = (const float*)d_in[8];
  float* out = (float*)d_out;

  float* ws = (float*)d_ws;
  float*  proj    = ws;                                   // 2048*3248
  float*  BC      = proj + (size_t)ROWS * D_PROJ;         // 2048*128
  float*  aDTf    = BC + (size_t)ROWS * 128;              // 48*1024*2
  float2* aDT     = (float2*)aDTf;
  float*  Tbuf    = aDTf + (size_t)2 * BATCH * NHEADS * SEQ;        // 768*4096 f32
  float*  Ebuf    = Tbuf + (size_t)BATCH * NHEADS * NCH * 4096;     // 1024
  float*  Sinbuf  = Ebuf + 1024;                          // 768*4096 f32
  float*  Woutbff = Sinbuf + (size_t)BATCH * NHEADS * NCH * 4096;   // scratch

  // packed bf16 buffers aliased onto dead f32 regions (lifetimes verified):
  //   upk   (3.1MB)  in Sinbuf region — dead before interchunk writes Sinbuf
  //   Winpk (4.9MB)  in Tbuf region   — dead before chunk_state writes Tbuf
  //   Ypk   (6.3MB)  in Tbuf region   — written after interchunk read Tbuf
  //   Wopk  (2.4MB)  standalone
  unsigned short* upk   = (unsigned short*)Sinbuf;
  unsigned short* Winpk = (unsigned short*)Tbuf;
  unsigned short* Ypk   = (unsigned short*)Tbuf;
  unsigned short* Wopk  = (unsigned short*)Woutbff;

  // cast+pack (one fused launch): 24*32 + 24*52 + 48*12 = 2592 blocks
  pack_all_kernel<<<KT_1 * RG_U + KT_1 * RG_WIN + KT_2 * RG_WO, 256, 0, stream>>>(
      u, Win, Wout, upk, Winpk, Wopk);

  // 1) proj = u @ Win.T   (packed operands, contiguous staging)
  gemm_bt_bf16<64, 128, 26, 32, false><<<832, 256, 0, stream>>>(
      upk, Winpk, proj, RG_U, RG_WIN, ROWS, D_PROJ, D_MODEL);

  // 2) LN(B), LN(C), a/DT
  prep_kernel<<<ROWS, 64, 0, stream>>>(proj, dt_bias, Bg, Bb, Cg, Cb, BC, aDT);

  // 3) chunked scan
  chunk_state_kernel<<<BATCH * NHEADS * NCH, 256, 0, stream>>>(proj, BC, aDT, Tbuf, Ebuf);
  interchunk_kernel<<<BATCH * NHEADS * 4, 256, 0, stream>>>(Tbuf, Ebuf, Sinbuf);
  chunk_output_kernel<<<BATCH * NHEADS * NCH, 256, 0, stream>>>(proj, BC, aDT, Sinbuf, Dv, Ypk);

  // 4) out = Y @ Wout.T   (packed operands)
  gemm_bt_bf16<64, 64, 12, 32, true><<<384, 256, 0, stream>>>(
      Ypk, Wopk, out, RG_U, RG_WO, ROWS, D_MODEL, D_INNER);
}

// Round 9
// 98.142 us; speedup vs baseline: 1.3083x; 1.0870x over previous
//
#include <hip/hip_runtime.h>
#include <cstdint>

#define D_MODEL   768
#define D_STATE   64
#define D_INNER   1536
#define NHEADS    24
#define HEADDIM   64
#define D_PROJ    3248
#define BATCH     2
#define SEQ       1024
#define ROWS      (BATCH*SEQ)   // 2048
#define LN_EPS    1e-5f
#define A_FLOOR   1e-4f
#define QC        64            // chunk length
#define NCH       (SEQ/QC)      // 16
#define LDT       68            // padded LDS stride (floats)

// packed-operand geometry: [kt][rg][c4][64 rows][8 bf16] (4KB per (kt,rg))
#define RG_U    32   // 2048/64 rowgroups (u and Ybuf)
#define RG_WIN  52   // 3328/64 (Win padded 3248->3328)
#define RG_WO   12   // 768/64  (Wout)
#define KT_1    24   // K=768/32
#define KT_2    48   // K=1536/32

typedef __attribute__((ext_vector_type(8))) short short8;
typedef __attribute__((ext_vector_type(4))) float f32x4;

// round-to-nearest-even f32 -> bf16 bits
__device__ __forceinline__ unsigned short f2bf(float f) {
  union { float f; uint32_t u; } v; v.f = f;
  uint32_t r = (v.u + 0x7FFFu + ((v.u >> 16) & 1u)) >> 16;
  return (unsigned short)r;
}

__device__ __forceinline__ void gload_lds16(const void* g, void* l) {
  __builtin_amdgcn_global_load_lds(
      (const __attribute__((address_space(1))) unsigned int*)g,
      (__attribute__((address_space(3))) unsigned int*)l, 16, 0, 0);
}

// counted vmcnt wait (T4)
template <int N>
__device__ __forceinline__ void wait_vm() {
  static_assert(N == 0 || N == 2 || N == 3 || N == 4 || N == 6 || N == 8,
                "unsupported vmcnt");
  if constexpr (N == 0) asm volatile("s_waitcnt vmcnt(0)" ::: "memory");
  else if constexpr (N == 2) asm volatile("s_waitcnt vmcnt(2)" ::: "memory");
  else if constexpr (N == 3) asm volatile("s_waitcnt vmcnt(3)" ::: "memory");
  else if constexpr (N == 4) asm volatile("s_waitcnt vmcnt(4)" ::: "memory");
  else if constexpr (N == 6) asm volatile("s_waitcnt vmcnt(6)" ::: "memory");
  else if constexpr (N == 8) asm volatile("s_waitcnt vmcnt(8)" ::: "memory");
}

// ---------------------------------------------------------------------------
// Pack f32 row-major -> bf16 [kt][rg][c][64][8].
// ---------------------------------------------------------------------------
__global__ __launch_bounds__(256) void pack_all_kernel(
    const float* __restrict__ u, const float* __restrict__ Win,
    const float* __restrict__ Wout, unsigned short* __restrict__ upk,
    unsigned short* __restrict__ Winpk, unsigned short* __restrict__ Wopk) {
  int b = blockIdx.x;
  const float* src; unsigned short* dst; int K, RG, kt, rg, srcRows;
  if (b < KT_1 * RG_U) {
    src = u; dst = upk; K = 768; RG = RG_U; kt = b / RG_U; rg = b % RG_U; srcRows = ROWS;
  } else if (b < KT_1 * RG_U + KT_1 * RG_WIN) {
    int i = b - KT_1 * RG_U;
    src = Win; dst = Winpk; K = 768; RG = RG_WIN; kt = i / RG_WIN; rg = i % RG_WIN; srcRows = D_PROJ;
  } else {
    int i = b - KT_1 * RG_U - KT_1 * RG_WIN;
    src = Wout; dst = Wopk; K = 1536; RG = RG_WO; kt = i / RG_WO; rg = i % RG_WO; srcRows = D_MODEL;
  }
  const int t = threadIdx.x;
  const int lr = t >> 2, cq = t & 3;
  const int R = rg * 64 + lr;
  float4 v0 = make_float4(0.f, 0.f, 0.f, 0.f), v1 = v0;
  if (R < srcRows) {
    const float* p = src + (size_t)R * K + kt * 32 + cq * 8;
    v0 = *(const float4*)p;
    v1 = *(const float4*)(p + 4);
  }
  ushort4 oa, ob;
  oa.x = f2bf(v0.x); oa.y = f2bf(v0.y); oa.z = f2bf(v0.z); oa.w = f2bf(v0.w);
  ob.x = f2bf(v1.x); ob.y = f2bf(v1.y); ob.z = f2bf(v1.z); ob.w = f2bf(v1.w);
  unsigned short* o = dst + ((size_t)(kt * RG + rg) * 4 + cq) * 512 + lr * 8;
  *(ushort4*)o = oa;
  *(ushort4*)(o + 4) = ob;
}

// ---------------------------------------------------------------------------
// MFMA bf16 GEMM (NT) on PACKED operands. 4-buf / prefetch-3 / 1 barrier/iter,
// XCD panel swizzle, optional split-K via blockIdx.y (partials to separate C).
// K parameter = per-split K. kt indices are relative to the split's offset.
// ---------------------------------------------------------------------------
template <int TBM, int TBN, int GX, int GY, bool XMAJOR>
__global__ __launch_bounds__(256) void gemm_bt_bf16(
    const unsigned short* __restrict__ A, const unsigned short* __restrict__ B,
    float* __restrict__ C, int aRG, int bRG, int M, int N, int K) {
  constexpr int MF = TBM / 32;
  constexpr int NF = TBN / 32;
  constexpr int NSA = TBM / 16;
  constexpr int NSB = TBN / 16;
  constexpr int LPW = (NSA + NSB) / 4;
  static_assert((NSA + NSB) % 4 == 0, "segments must split evenly over waves");
  constexpr int NWG = GX * GY;
  constexpr int PER = NWG / 8;
  static_assert(NWG % 8 == 0, "grid must split evenly over 8 XCDs");
  __shared__ unsigned short Asm[4][TBM * 32];
  __shared__ unsigned short Bsm[4][TBN * 32];

  const int tid = threadIdx.x;
  const int wv = tid >> 6, lane = tid & 63;
  const int kTiles = K >> 5;

  // split-K: offset operands and output by split index
  const int sk = blockIdx.y;
  A += (size_t)sk * kTiles * aRG * 2048;
  B += (size_t)sk * kTiles * bRG * 2048;
  C += (size_t)sk * M * N;

  // XCD-chunked bijective swizzle
  const int g = (blockIdx.x & 7) * PER + (blockIdx.x >> 3);
  int bx, by;
  if constexpr (XMAJOR) { by = g / GX; bx = g - by * GX; }
  else                  { bx = g / GY; by = g - bx * GY; }
  const int bm = by * TBM, bn = bx * TBN;

  const int wm = (wv & 1) * (TBM / 2);
  const int wn = (wv >> 1) * (TBN / 2);
  const int gq = lane >> 4, r = lane & 15;

  f32x4 acc[MF][NF];
#pragma unroll
  for (int i = 0; i < MF; ++i)
#pragma unroll
    for (int j = 0; j < NF; ++j) acc[i][j] = (f32x4){0.f, 0.f, 0.f, 0.f};

  auto stage = [&](int kt, int buf) {
    for (int s = wv; s < NSA + NSB; s += 4) {
      if (s < NSA) {
        const unsigned short* src =
            A + ((size_t)kt * aRG + (bm >> 6) + (s >> 2)) * 2048 + (s & 3) * 512 + lane * 8;
        gload_lds16(src, (void*)(&Asm[buf][s * 512]));
      } else {
        int s2 = s - NSA;
        const unsigned short* src =
            B + ((size_t)kt * bRG + (bn >> 6) + (s2 >> 2)) * 2048 + (s2 & 3) * 512 + lane * 8;
        gload_lds16(src, (void*)(&Bsm[buf][s2 * 512]));
      }
    }
  };

  stage(0, 0);
  stage(1, 1);
  stage(2, 2);

  for (int t = 0; t < kTiles; ++t) {
    const int cur = t & 3;
    if (t + 2 < kTiles)      wait_vm<2 * LPW>();
    else if (t + 1 < kTiles) wait_vm<LPW>();
    else                     wait_vm<0>();
    __builtin_amdgcn_s_barrier();
    asm volatile("" ::: "memory");

    if (t + 3 < kTiles) stage(t + 3, (t + 3) & 3);

    short8 a[MF], b[NF];
#pragma unroll
    for (int mf = 0; mf < MF; ++mf) {
      int ra = wm + mf * 16 + r;
      a[mf] = *(const short8*)&Asm[cur][(ra >> 6) * 2048 + gq * 512 + (ra & 63) * 8];
    }
#pragma unroll
    for (int nf = 0; nf < NF; ++nf) {
      int rb = wn + nf * 16 + r;
      b[nf] = *(const short8*)&Bsm[cur][(rb >> 6) * 2048 + gq * 512 + (rb & 63) * 8];
    }
#pragma unroll
    for (int mf = 0; mf < MF; ++mf)
#pragma unroll
      for (int nf = 0; nf < NF; ++nf)
        acc[mf][nf] = __builtin_amdgcn_mfma_f32_16x16x32_bf16(a[mf], b[nf], acc[mf][nf], 0, 0, 0);
  }

  // C write: D row = (lane>>4)*4 + q, col = lane&15 (m89-verified layout)
#pragma unroll
  for (int mf = 0; mf < MF; ++mf) {
#pragma unroll
    for (int nf = 0; nf < NF; ++nf) {
      int col = bn + wn + nf * 16 + r;
      if (col < N) {
#pragma unroll
        for (int q = 0; q < 4; ++q) {
          int row = bm + wm + mf * 16 + gq * 4 + q;
          C[(size_t)row * N + col] = acc[mf][nf][q];
        }
      }
    }
  }
}

// ---------------------------------------------------------------------------
// split-K reduce: out = p0 + p1 (f32, float4 per thread)
// ---------------------------------------------------------------------------
__global__ __launch_bounds__(256) void reduce2_kernel(
    const float* __restrict__ P, float* __restrict__ out, int n4) {
  int i = blockIdx.x * 256 + threadIdx.x;
  if (i < n4) {
    float4 a = *(const float4*)(P + (size_t)i * 4);
    float4 b = *(const float4*)(P + (size_t)(n4 + i) * 4);
    a.x += b.x; a.y += b.y; a.z += b.z; a.w += b.w;
    *(float4*)(out + (size_t)i * 4) = a;
  }
}

// ---------------------------------------------------------------------------
// Prep: LN(B), LN(C) -> BC; a = A*DT (log-decay), DT -> aDT
// ---------------------------------------------------------------------------
__device__ __forceinline__ float softplusf(float x) {
  return (x > 20.f) ? x : log1pf(expf(x));
}

__device__ __forceinline__ float wave_sum64(float v) {
#pragma unroll
  for (int o = 32; o > 0; o >>= 1) v += __shfl_xor(v, o);
  return v;
}

__global__ __launch_bounds__(64) void prep_kernel(
    const float* __restrict__ proj, const float* __restrict__ dt_bias,
    const float* __restrict__ Bg, const float* __restrict__ Bb,
    const float* __restrict__ Cg, const float* __restrict__ Cb,
    float* __restrict__ BC, float2* __restrict__ aDT) {
  const int r = blockIdx.x;
  const int lane = threadIdx.x;
  const float* p = proj + (size_t)r * D_PROJ;

  float bp = p[2 * D_INNER + lane];
  float cp = p[2 * D_INNER + D_STATE + lane];

  float mb = wave_sum64(bp) * (1.f / 64.f);
  float mc = wave_sum64(cp) * (1.f / 64.f);
  float db = bp - mb, dc = cp - mc;
  float vb = wave_sum64(db * db) * (1.f / 64.f);
  float vc = wave_sum64(dc * dc) * (1.f / 64.f);
  float bn = db * rsqrtf(vb + LN_EPS) * Bg[lane] + Bb[lane];
  float cn = dc * rsqrtf(vc + LN_EPS) * Cg[lane] + Cb[lane];
  BC[(size_t)r * 128 + lane]      = bn;
  BC[(size_t)r * 128 + 64 + lane] = cn;

  if (lane < NHEADS) {
    float ddt = p[2 * D_INNER + 2 * D_STATE + lane];
    float dA  = p[2 * D_INNER + 2 * D_STATE + NHEADS + lane];
    float DT = softplusf(ddt + dt_bias[lane]);
    float Aa = fminf(-softplusf(dA), -A_FLOOR);
    int b = r >> 10;
    int t = r & 1023;
    aDT[((size_t)(b * NHEADS + lane) << 10) + t] = make_float2(Aa * DT, DT);
  }
}

__device__ __forceinline__ float wave_prefix_incl(float v, int lane) {
#pragma unroll
  for (int o = 1; o < 64; o <<= 1) {
    float w = __shfl_up(v, o);
    if (lane >= o) v += w;
  }
  return v;
}

// ---------------------------------------------------------------------------
// chunk_state: T_c[n][p] = sum_s DT_s*exp(csum_end - csum_s) * B_s[n]*x_s[p]
// ---------------------------------------------------------------------------
__global__ __launch_bounds__(256) void chunk_state_kernel(
    const float* __restrict__ proj, const float* __restrict__ BC,
    const float2* __restrict__ aDT, float* __restrict__ Tbuf,
    float* __restrict__ Ebuf) {
  const int blk = blockIdx.x;
  const int c = blk & (NCH - 1), bh = blk >> 4;
  const int b = bh / NHEADS, hh = bh % NHEADS;
  const int tid = threadIdx.x;

  __shared__ float Bs[QC][LDT];
  __shared__ float Xs[QC][LDT];
  __shared__ float coeff[QC];
  __shared__ float etot[1];

  if (tid < 64) {
    float2 ad = aDT[((size_t)bh << 10) + c * QC + tid];
    float cs = wave_prefix_incl(ad.x, tid);
    float tot = __shfl(cs, 63);
    coeff[tid] = ad.y * __expf(tot - cs);
    if (tid == 63) etot[0] = __expf(tot);
  }
  __syncthreads();

  for (int i = tid; i < 1024; i += 256) {
    int s = i >> 4;
    int q = (i & 15) * 4;
    int r = b * SEQ + c * QC + s;
    *(float4*)&Bs[s][q] = *(const float4*)(BC + (size_t)r * 128 + q);
    float4 xv = *(const float4*)(proj + (size_t)r * D_PROJ + D_INNER + hh * 64 + q);
    float cf = coeff[s];
    xv.x *= cf; xv.y *= cf; xv.z *= cf; xv.w *= cf;
    *(float4*)&Xs[s][q] = xv;
  }
  __syncthreads();

  const int ni = (tid & 15) * 4, pi = (tid >> 4) * 4;
  float acc[4][4];
#pragma unroll
  for (int i = 0; i < 4; ++i)
#pragma unroll
    for (int j = 0; j < 4; ++j) acc[i][j] = 0.f;

  for (int s = 0; s < QC; ++s) {
    float bn[4], xp[4];
    *(float4*)bn = *(float4*)&Bs[s][ni];
    *(float4*)xp = *(float4*)&Xs[s][pi];
#pragma unroll
    for (int i = 0; i < 4; ++i)
#pragma unroll
      for (int j = 0; j < 4; ++j)
        acc[i][j] = fmaf(bn[i], xp[j], acc[i][j]);
  }

  float* T = Tbuf + (size_t)blk * 4096;
#pragma unroll
  for (int i = 0; i < 4; ++i)
    *(float4*)(T + (size_t)(ni + i) * 64 + pi) =
        make_float4(acc[i][0], acc[i][1], acc[i][2], acc[i][3]);
  if (tid == 0) Ebuf[blk] = etot[0];
}

// ---------------------------------------------------------------------------
// interchunk: S_in[c+1] = E_c * S_in[c] + T_c
// ---------------------------------------------------------------------------
__global__ __launch_bounds__(256) void interchunk_kernel(
    const float* __restrict__ Tbuf, const float* __restrict__ Ebuf,
    float* __restrict__ Sinbuf) {
  const int bh = blockIdx.x >> 2, part = blockIdx.x & 3;
  const int tid = threadIdx.x;
  const size_t eo = (size_t)part * 1024 + tid * 4;
  float4 s = make_float4(0.f, 0.f, 0.f, 0.f);
#pragma unroll
  for (int c = 0; c < NCH; ++c) {
    size_t off = ((size_t)(bh * NCH + c)) * 4096 + eo;
    *(float4*)(Sinbuf + off) = s;
    float E = Ebuf[bh * NCH + c];
    float4 t4 = *(const float4*)(Tbuf + off);
    s.x = fmaf(E, s.x, t4.x);
    s.y = fmaf(E, s.y, t4.y);
    s.z = fmaf(E, s.z, t4.z);
    s.w = fmaf(E, s.w, t4.w);
  }
}

// ---------------------------------------------------------------------------
// chunk_output: intra+inter chunk Y, + D*x, silu(z) gate -> PACKED bf16 Ybuf
// ---------------------------------------------------------------------------
__global__ __launch_bounds__(256) void chunk_output_kernel(
    const float* __restrict__ proj, const float* __restrict__ BC,
    const float2* __restrict__ aDT, const float* __restrict__ Sinbuf,
    const float* __restrict__ Dv, unsigned short* __restrict__ Ybf) {
  const int blk = blockIdx.x;
  const int c = blk & (NCH - 1), bh = blk >> 4;
  const int b = bh / NHEADS, hh = bh % NHEADS;
  const int tid = threadIdx.x;

  __shared__ float smem[3 * 64 * LDT];
  __shared__ float csum[QC];
  __shared__ float DTs[QC];
  float (*CcT)[LDT] = (float(*)[LDT])smem;
  float (*BcT)[LDT] = (float(*)[LDT])(smem + 64 * LDT);
  float (*Sin)[LDT] = (float(*)[LDT])(smem + 2 * 64 * LDT);
  float (*Wb)[LDT]  = CcT;
  float (*Xs)[LDT]  = BcT;

  if (tid < 64) {
    float2 ad = aDT[((size_t)bh << 10) + c * QC + tid];
    csum[tid] = wave_prefix_incl(ad.x, tid);
    DTs[tid] = ad.y;
  }

  const size_t sin_base = (size_t)blk * 4096;
  for (int i = tid; i < 1024; i += 256) {
    int tt = i >> 4;
    int q = (i & 15) * 4;
    int r = b * SEQ + c * QC + tt;
    float4 bv = *(const float4*)(BC + (size_t)r * 128 + q);
    float4 cv = *(const float4*)(BC + (size_t)r * 128 + 64 + q);
    BcT[q + 0][tt] = bv.x; BcT[q + 1][tt] = bv.y;
    BcT[q + 2][tt] = bv.z; BcT[q + 3][tt] = bv.w;
    CcT[q + 0][tt] = cv.x; CcT[q + 1][tt] = cv.y;
    CcT[q + 2][tt] = cv.z; CcT[q + 3][tt] = cv.w;
    *(float4*)&Sin[tt][q] = *(const float4*)(Sinbuf + sin_base + (size_t)tt * 64 + q);
  }
  __syncthreads();

  const int ti = (tid & 15) * 4, si = (tid >> 4) * 4;
  float acc1[4][4], acc2[4][4];
#pragma unroll
  for (int i = 0; i < 4; ++i)
#pragma unroll
    for (int j = 0; j < 4; ++j) { acc1[i][j] = 0.f; acc2[i][j] = 0.f; }

  for (int n = 0; n < 64; ++n) {
    float cv[4], bv[4], sv[4];
    *(float4*)cv = *(float4*)&CcT[n][ti];
    *(float4*)bv = *(float4*)&BcT[n][si];
    *(float4*)sv = *(float4*)&Sin[n][si];
#pragma unroll
    for (int i = 0; i < 4; ++i)
#pragma unroll
      for (int j = 0; j < 4; ++j) {
        acc1[i][j] = fmaf(cv[i], bv[j], acc1[i][j]);
        acc2[i][j] = fmaf(cv[i], sv[j], acc2[i][j]);
      }
  }
  __syncthreads();

#pragma unroll
  for (int j = 0; j < 4; ++j) {
    int s = si + j;
    float dts = DTs[s], cs = csum[s];
    float w4[4];
#pragma unroll
    for (int i = 0; i < 4; ++i) {
      int t = ti + i;
      w4[i] = (s <= t) ? acc1[i][j] * __expf(csum[t] - cs) * dts : 0.f;
    }
    *(float4*)&Wb[s][ti] = *(float4*)w4;
  }
#pragma unroll
  for (int i = 0; i < 4; ++i) {
    float d = __expf(csum[ti + i]);
#pragma unroll
    for (int j = 0; j < 4; ++j) acc2[i][j] *= d;
  }
  for (int i = tid; i < 1024; i += 256) {
    int s = i >> 4;
    int q = (i & 15) * 4;
    int r = b * SEQ + c * QC + s;
    *(float4*)&Xs[s][q] = *(const float4*)(proj + (size_t)r * D_PROJ + D_INNER + hh * 64 + q);
  }
  __syncthreads();

  for (int s = 0; s < 64; ++s) {
    float wv[4], xv[4];
    *(float4*)wv = *(float4*)&Wb[s][ti];
    *(float4*)xv = *(float4*)&Xs[s][si];
#pragma unroll
    for (int i = 0; i < 4; ++i)
#pragma unroll
      for (int j = 0; j < 4; ++j)
        acc2[i][j] = fmaf(wv[i], xv[j], acc2[i][j]);
  }

  // epilogue -> packed Ybf: kt = col/32, cseg = (col%32)/8, rg = r/64
  const float Dh = Dv[hh];
  const int kt = hh * 2 + (si >> 5);
  const int cseg = (si >> 3) & 3;
  const int j0 = si & 7;
  const int rg = b * 16 + c;
#pragma unroll
  for (int i = 0; i < 4; ++i) {
    int t = ti + i;
    int r = b * SEQ + c * QC + t;
    float zv[4];
    *(float4*)zv = *(const float4*)(proj + (size_t)r * D_PROJ + hh * 64 + si);
    ushort4 o;
    unsigned short* op = (unsigned short*)&o;
#pragma unroll
    for (int j = 0; j < 4; ++j) {
      float x = Xs[t][si + j];
      float y = acc2[i][j] + Dh * x;
      float z = zv[j];
      op[j] = f2bf(y * (z / (1.f + __expf(-z))));
    }
    *(ushort4*)(Ybf + ((size_t)(kt * RG_U + rg) * 4 + cseg) * 512 + t * 8 + j0) = o;
  }
}

// ---------------------------------------------------------------------------
// Launch
// ---------------------------------------------------------------------------
extern "C" void kernel_launch(void* const* d_in, const int* in_sizes, int n_in,
                              void* d_out, int out_size, void* d_ws, size_t ws_size,
                              hipStream_t stream) {
  const float* u       = (const float*)d_in[0];
  const float* Win     = (const float*)d_in[1];
  const float* Wout    = (const float*)d_in[2];
  const float* dt_bias = (const float*)d_in[3];
  const float* Dv      = (const float*)d_in[4];
  const float* Bg      = (const float*)d_in[5];
  const float* Bb      = (const float*)d_in[6];
  const float* Cg      = (const float*)d_in[7];
  const float* Cb      = (const float*)d_in[8];
  float* out = (float*)d_out;

  float* ws = (float*)d_ws;
  float*  proj    = ws;                                   // 2048*3248
  float*  BC      = proj + (size_t)ROWS * D_PROJ;         // 2048*128
  float*  aDTf    = BC + (size_t)ROWS * 128;              // 48*1024*2
  float2* aDT     = (float2*)aDTf;
  float*  Tbuf    = aDTf + (size_t)2 * BATCH * NHEADS * SEQ;        // 768*4096 f32
  float*  Ebuf    = Tbuf + (size_t)BATCH * NHEADS * NCH * 4096;     // 1024
  float*  Sinbuf  = Ebuf + 1024;                          // 768*4096 f32
  float*  Woutbff = Sinbuf + (size_t)BATCH * NHEADS * NCH * 4096;   // Wopk region
  float*  Pbuf    = Woutbff + 589824;                     // 2 * 2048*768 f32 partials

  // packed bf16 buffers aliased onto dead f32 regions (lifetimes verified):
  unsigned short* upk   = (unsigned short*)Sinbuf;   // dead before interchunk
  unsigned short* Winpk = (unsigned short*)Tbuf;     // dead before chunk_state
  unsigned short* Ypk   = (unsigned short*)Tbuf;     // after interchunk read Tbuf
  unsigned short* Wopk  = (unsigned short*)Woutbff;  // standalone

  // cast+pack (one fused launch)
  pack_all_kernel<<<KT_1 * RG_U + KT_1 * RG_WIN + KT_2 * RG_WO, 256, 0, stream>>>(
      u, Win, Wout, upk, Winpk, Wopk);

  // 1) proj = u @ Win.T   (128x128 tile, 16 MFMA/wave-iter)
  gemm_bt_bf16<128, 128, 26, 16, false><<<416, 256, 0, stream>>>(
      upk, Winpk, proj, RG_U, RG_WIN, ROWS, D_PROJ, D_MODEL);

  // 2) LN(B), LN(C), a/DT
  prep_kernel<<<ROWS, 64, 0, stream>>>(proj, dt_bias, Bg, Bb, Cg, Cb, BC, aDT);

  // 3) chunked scan
  chunk_state_kernel<<<BATCH * NHEADS * NCH, 256, 0, stream>>>(proj, BC, aDT, Tbuf, Ebuf);
  interchunk_kernel<<<BATCH * NHEADS * 4, 256, 0, stream>>>(Tbuf, Ebuf, Sinbuf);
  chunk_output_kernel<<<BATCH * NHEADS * NCH, 256, 0, stream>>>(proj, BC, aDT, Sinbuf, Dv, Ypk);

  // 4) out = Y @ Wout.T   (split-K=2: partials -> reduce)
  gemm_bt_bf16<64, 64, 12, 32, true><<<dim3(384, 2), 256, 0, stream>>>(
      Ypk, Wopk, Pbuf, RG_U, RG_WO, ROWS, D_MODEL, D_INNER / 2);
  reduce2_kernel<<<1536, 256, 0, stream>>>(Pbuf, out, ROWS * D_MODEL / 4);
}

// Round 10
// 81.860 us; speedup vs baseline: 1.5685x; 1.1989x over previous
//
#include <hip/hip_runtime.h>
#include <cstdint>

#define D_MODEL   768
#define D_STATE   64
#define D_INNER   1536
#define NHEADS    24
#define HEADDIM   64
#define D_PROJ    3248
#define BATCH     2
#define SEQ       1024
#define ROWS      (BATCH*SEQ)   // 2048
#define LN_EPS    1e-5f
#define A_FLOOR   1e-4f
#define QC        64            // chunk length
#define NCH       (SEQ/QC)      // 16
#define LSTR      72            // LDS row stride in shorts (144B = 9*16B)

// packed-operand geometry: [kt][rg][c4][64 rows][8 bf16] (4KB per (kt,rg))
#define RG_U    32   // 2048/64 rowgroups (u and Ybuf)
#define RG_WIN  52   // 3328/64 (Win padded 3248->3328)
#define RG_WO   12   // 768/64  (Wout)
#define KT_1    24   // K=768/32
#define KT_2    48   // K=1536/32

typedef __attribute__((ext_vector_type(8))) short short8;
typedef __attribute__((ext_vector_type(4))) float f32x4;

// round-to-nearest-even f32 -> bf16 bits
__device__ __forceinline__ unsigned short f2bf(float f) {
  union { float f; uint32_t u; } v; v.f = f;
  uint32_t r = (v.u + 0x7FFFu + ((v.u >> 16) & 1u)) >> 16;
  return (unsigned short)r;
}

__device__ __forceinline__ void gload_lds16(const void* g, void* l) {
  __builtin_amdgcn_global_load_lds(
      (const __attribute__((address_space(1))) unsigned int*)g,
      (__attribute__((address_space(3))) unsigned int*)l, 16, 0, 0);
}

// counted vmcnt wait (T4)
template <int N>
__device__ __forceinline__ void wait_vm() {
  static_assert(N == 0 || N == 2 || N == 3 || N == 4 || N == 6 || N == 8,
                "unsupported vmcnt");
  if constexpr (N == 0) asm volatile("s_waitcnt vmcnt(0)" ::: "memory");
  else if constexpr (N == 2) asm volatile("s_waitcnt vmcnt(2)" ::: "memory");
  else if constexpr (N == 3) asm volatile("s_waitcnt vmcnt(3)" ::: "memory");
  else if constexpr (N == 4) asm volatile("s_waitcnt vmcnt(4)" ::: "memory");
  else if constexpr (N == 6) asm volatile("s_waitcnt vmcnt(6)" ::: "memory");
  else if constexpr (N == 8) asm volatile("s_waitcnt vmcnt(8)" ::: "memory");
}

// ---------------------------------------------------------------------------
// Pack f32 row-major -> bf16 [kt][rg][c][64][8].
// ---------------------------------------------------------------------------
__global__ __launch_bounds__(256) void pack_all_kernel(
    const float* __restrict__ u, const float* __restrict__ Win,
    const float* __restrict__ Wout, unsigned short* __restrict__ upk,
    unsigned short* __restrict__ Winpk, unsigned short* __restrict__ Wopk) {
  int b = blockIdx.x;
  const float* src; unsigned short* dst; int K, RG, kt, rg, srcRows;
  if (b < KT_1 * RG_U) {
    src = u; dst = upk; K = 768; RG = RG_U; kt = b / RG_U; rg = b % RG_U; srcRows = ROWS;
  } else if (b < KT_1 * RG_U + KT_1 * RG_WIN) {
    int i = b - KT_1 * RG_U;
    src = Win; dst = Winpk; K = 768; RG = RG_WIN; kt = i / RG_WIN; rg = i % RG_WIN; srcRows = D_PROJ;
  } else {
    int i = b - KT_1 * RG_U - KT_1 * RG_WIN;
    src = Wout; dst = Wopk; K = 1536; RG = RG_WO; kt = i / RG_WO; rg = i % RG_WO; srcRows = D_MODEL;
  }
  const int t = threadIdx.x;
  const int lr = t >> 2, cq = t & 3;
  const int R = rg * 64 + lr;
  float4 v0 = make_float4(0.f, 0.f, 0.f, 0.f), v1 = v0;
  if (R < srcRows) {
    const float* p = src + (size_t)R * K + kt * 32 + cq * 8;
    v0 = *(const float4*)p;
    v1 = *(const float4*)(p + 4);
  }
  ushort4 oa, ob;
  oa.x = f2bf(v0.x); oa.y = f2bf(v0.y); oa.z = f2bf(v0.z); oa.w = f2bf(v0.w);
  ob.x = f2bf(v1.x); ob.y = f2bf(v1.y); ob.z = f2bf(v1.z); ob.w = f2bf(v1.w);
  unsigned short* o = dst + ((size_t)(kt * RG + rg) * 4 + cq) * 512 + lr * 8;
  *(ushort4*)o = oa;
  *(ushort4*)(o + 4) = ob;
}

// ---------------------------------------------------------------------------
// MFMA bf16 GEMM (NT) on PACKED operands. 4-buf / prefetch-3 / 1 barrier/iter,
// XCD panel swizzle, optional split-K via blockIdx.y.
// ---------------------------------------------------------------------------
template <int TBM, int TBN, int GX, int GY, bool XMAJOR>
__global__ __launch_bounds__(256) void gemm_bt_bf16(
    const unsigned short* __restrict__ A, const unsigned short* __restrict__ B,
    float* __restrict__ C, int aRG, int bRG, int M, int N, int K) {
  constexpr int MF = TBM / 32;
  constexpr int NF = TBN / 32;
  constexpr int NSA = TBM / 16;
  constexpr int NSB = TBN / 16;
  constexpr int LPW = (NSA + NSB) / 4;
  static_assert((NSA + NSB) % 4 == 0, "segments must split evenly over waves");
  constexpr int NWG = GX * GY;
  constexpr int PER = NWG / 8;
  static_assert(NWG % 8 == 0, "grid must split evenly over 8 XCDs");
  __shared__ unsigned short Asm[4][TBM * 32];
  __shared__ unsigned short Bsm[4][TBN * 32];

  const int tid = threadIdx.x;
  const int wv = tid >> 6, lane = tid & 63;
  const int kTiles = K >> 5;

  const int sk = blockIdx.y;
  A += (size_t)sk * kTiles * aRG * 2048;
  B += (size_t)sk * kTiles * bRG * 2048;
  C += (size_t)sk * M * N;

  const int g = (blockIdx.x & 7) * PER + (blockIdx.x >> 3);
  int bx, by;
  if constexpr (XMAJOR) { by = g / GX; bx = g - by * GX; }
  else                  { bx = g / GY; by = g - bx * GY; }
  const int bm = by * TBM, bn = bx * TBN;

  const int wm = (wv & 1) * (TBM / 2);
  const int wn = (wv >> 1) * (TBN / 2);
  const int gq = lane >> 4, r = lane & 15;

  f32x4 acc[MF][NF];
#pragma unroll
  for (int i = 0; i < MF; ++i)
#pragma unroll
    for (int j = 0; j < NF; ++j) acc[i][j] = (f32x4){0.f, 0.f, 0.f, 0.f};

  auto stage = [&](int kt, int buf) {
    for (int s = wv; s < NSA + NSB; s += 4) {
      if (s < NSA) {
        const unsigned short* src =
            A + ((size_t)kt * aRG + (bm >> 6) + (s >> 2)) * 2048 + (s & 3) * 512 + lane * 8;
        gload_lds16(src, (void*)(&Asm[buf][s * 512]));
      } else {
        int s2 = s - NSA;
        const unsigned short* src =
            B + ((size_t)kt * bRG + (bn >> 6) + (s2 >> 2)) * 2048 + (s2 & 3) * 512 + lane * 8;
        gload_lds16(src, (void*)(&Bsm[buf][s2 * 512]));
      }
    }
  };

  stage(0, 0);
  stage(1, 1);
  stage(2, 2);

  for (int t = 0; t < kTiles; ++t) {
    const int cur = t & 3;
    if (t + 2 < kTiles)      wait_vm<2 * LPW>();
    else if (t + 1 < kTiles) wait_vm<LPW>();
    else                     wait_vm<0>();
    __builtin_amdgcn_s_barrier();
    asm volatile("" ::: "memory");

    if (t + 3 < kTiles) stage(t + 3, (t + 3) & 3);

    short8 a[MF], b[NF];
#pragma unroll
    for (int mf = 0; mf < MF; ++mf) {
      int ra = wm + mf * 16 + r;
      a[mf] = *(const short8*)&Asm[cur][(ra >> 6) * 2048 + gq * 512 + (ra & 63) * 8];
    }
#pragma unroll
    for (int nf = 0; nf < NF; ++nf) {
      int rb = wn + nf * 16 + r;
      b[nf] = *(const short8*)&Bsm[cur][(rb >> 6) * 2048 + gq * 512 + (rb & 63) * 8];
    }
#pragma unroll
    for (int mf = 0; mf < MF; ++mf)
#pragma unroll
      for (int nf = 0; nf < NF; ++nf)
        acc[mf][nf] = __builtin_amdgcn_mfma_f32_16x16x32_bf16(a[mf], b[nf], acc[mf][nf], 0, 0, 0);
  }

#pragma unroll
  for (int mf = 0; mf < MF; ++mf) {
#pragma unroll
    for (int nf = 0; nf < NF; ++nf) {
      int col = bn + wn + nf * 16 + r;
      if (col < N) {
#pragma unroll
        for (int q = 0; q < 4; ++q) {
          int row = bm + wm + mf * 16 + gq * 4 + q;
          C[(size_t)row * N + col] = acc[mf][nf][q];
        }
      }
    }
  }
}

// ---------------------------------------------------------------------------
// split-K reduce: out = p0 + p1
// ---------------------------------------------------------------------------
__global__ __launch_bounds__(256) void reduce2_kernel(
    const float* __restrict__ P, float* __restrict__ out, int n4) {
  int i = blockIdx.x * 256 + threadIdx.x;
  if (i < n4) {
    float4 a = *(const float4*)(P + (size_t)i * 4);
    float4 b = *(const float4*)(P + (size_t)(n4 + i) * 4);
    a.x += b.x; a.y += b.y; a.z += b.z; a.w += b.w;
    *(float4*)(out + (size_t)i * 4) = a;
  }
}

// ---------------------------------------------------------------------------
// Prep: LN(B), LN(C) -> BC; a = A*DT (log-decay), DT -> aDT
// ---------------------------------------------------------------------------
__device__ __forceinline__ float softplusf(float x) {
  return (x > 20.f) ? x : log1pf(expf(x));
}

__device__ __forceinline__ float wave_sum64(float v) {
#pragma unroll
  for (int o = 32; o > 0; o >>= 1) v += __shfl_xor(v, o);
  return v;
}

__global__ __launch_bounds__(64) void prep_kernel(
    const float* __restrict__ proj, const float* __restrict__ dt_bias,
    const float* __restrict__ Bg, const float* __restrict__ Bb,
    const float* __restrict__ Cg, const float* __restrict__ Cb,
    float* __restrict__ BC, float2* __restrict__ aDT) {
  const int r = blockIdx.x;
  const int lane = threadIdx.x;
  const float* p = proj + (size_t)r * D_PROJ;

  float bp = p[2 * D_INNER + lane];
  float cp = p[2 * D_INNER + D_STATE + lane];

  float mb = wave_sum64(bp) * (1.f / 64.f);
  float mc = wave_sum64(cp) * (1.f / 64.f);
  float db = bp - mb, dc = cp - mc;
  float vb = wave_sum64(db * db) * (1.f / 64.f);
  float vc = wave_sum64(dc * dc) * (1.f / 64.f);
  float bn = db * rsqrtf(vb + LN_EPS) * Bg[lane] + Bb[lane];
  float cn = dc * rsqrtf(vc + LN_EPS) * Cg[lane] + Cb[lane];
  BC[(size_t)r * 128 + lane]      = bn;
  BC[(size_t)r * 128 + 64 + lane] = cn;

  if (lane < NHEADS) {
    float ddt = p[2 * D_INNER + 2 * D_STATE + lane];
    float dA  = p[2 * D_INNER + 2 * D_STATE + NHEADS + lane];
    float DT = softplusf(ddt + dt_bias[lane]);
    float Aa = fminf(-softplusf(dA), -A_FLOOR);
    int b = r >> 10;
    int t = r & 1023;
    aDT[((size_t)(b * NHEADS + lane) << 10) + t] = make_float2(Aa * DT, DT);
  }
}

__device__ __forceinline__ float wave_prefix_incl(float v, int lane) {
#pragma unroll
  for (int o = 1; o < 64; o <<= 1) {
    float w = __shfl_up(v, o);
    if (lane >= o) v += w;
  }
  return v;
}

// ---------------------------------------------------------------------------
// chunk_state (MFMA): T[n][p] = sum_s B[s][n] * (coeff_s * x[s][p])
// LDS: BT[n][s], XT[p][s] bf16, row stride LSTR. 8 MFMA/wave.
// ---------------------------------------------------------------------------
__global__ __launch_bounds__(256) void chunk_state_kernel(
    const float* __restrict__ proj, const float* __restrict__ BC,
    const float2* __restrict__ aDT, float* __restrict__ Tbuf,
    float* __restrict__ Ebuf) {
  const int blk = blockIdx.x;
  const int c = blk & (NCH - 1), bh = blk >> 4;
  const int b = bh / NHEADS, hh = bh % NHEADS;
  const int tid = threadIdx.x;

  __shared__ unsigned short BT[64 * LSTR];  // [n][s]
  __shared__ unsigned short XT[64 * LSTR];  // [p][s]
  __shared__ float coeff[QC];
  __shared__ float etot[1];

  if (tid < 64) {
    float2 ad = aDT[((size_t)bh << 10) + c * QC + tid];
    float cs = wave_prefix_incl(ad.x, tid);
    float tot = __shfl(cs, 63);
    coeff[tid] = ad.y * __expf(tot - cs);
    if (tid == 63) etot[0] = __expf(tot);
  }
  __syncthreads();

  for (int i = tid; i < 1024; i += 256) {
    int s = i >> 4;
    int q = (i & 15) * 4;
    int r = b * SEQ + c * QC + s;
    float4 bv = *(const float4*)(BC + (size_t)r * 128 + q);
    float4 xv = *(const float4*)(proj + (size_t)r * D_PROJ + D_INNER + hh * 64 + q);
    float cf = coeff[s];
    BT[(q + 0) * LSTR + s] = f2bf(bv.x);
    BT[(q + 1) * LSTR + s] = f2bf(bv.y);
    BT[(q + 2) * LSTR + s] = f2bf(bv.z);
    BT[(q + 3) * LSTR + s] = f2bf(bv.w);
    XT[(q + 0) * LSTR + s] = f2bf(xv.x * cf);
    XT[(q + 1) * LSTR + s] = f2bf(xv.y * cf);
    XT[(q + 2) * LSTR + s] = f2bf(xv.z * cf);
    XT[(q + 3) * LSTR + s] = f2bf(xv.w * cf);
  }
  __syncthreads();

  const int w = tid >> 6, l = tid & 63;
  const int r16 = l & 15, g = l >> 4;
  f32x4 acc[4];
#pragma unroll
  for (int i = 0; i < 4; ++i) acc[i] = (f32x4){0.f, 0.f, 0.f, 0.f};

#pragma unroll
  for (int kk = 0; kk < 2; ++kk) {
    short8 a = *(const short8*)&BT[(w * 16 + r16) * LSTR + kk * 32 + g * 8];
#pragma unroll
    for (int pf = 0; pf < 4; ++pf) {
      short8 bf = *(const short8*)&XT[(pf * 16 + r16) * LSTR + kk * 32 + g * 8];
      acc[pf] = __builtin_amdgcn_mfma_f32_16x16x32_bf16(a, bf, acc[pf], 0, 0, 0);
    }
  }

  float* T = Tbuf + (size_t)blk * 4096;
#pragma unroll
  for (int pf = 0; pf < 4; ++pf)
#pragma unroll
    for (int q = 0; q < 4; ++q)
      T[(size_t)(w * 16 + g * 4 + q) * 64 + pf * 16 + r16] = acc[pf][q];
  if (tid == 0) Ebuf[blk] = etot[0];
}

// ---------------------------------------------------------------------------
// interchunk: S_in[c+1] = E_c * S_in[c] + T_c
// ---------------------------------------------------------------------------
__global__ __launch_bounds__(256) void interchunk_kernel(
    const float* __restrict__ Tbuf, const float* __restrict__ Ebuf,
    float* __restrict__ Sinbuf) {
  const int bh = blockIdx.x >> 2, part = blockIdx.x & 3;
  const int tid = threadIdx.x;
  const size_t eo = (size_t)part * 1024 + tid * 4;
  float4 s = make_float4(0.f, 0.f, 0.f, 0.f);
#pragma unroll
  for (int c = 0; c < NCH; ++c) {
    size_t off = ((size_t)(bh * NCH + c)) * 4096 + eo;
    *(float4*)(Sinbuf + off) = s;
    float E = Ebuf[bh * NCH + c];
    float4 t4 = *(const float4*)(Tbuf + off);
    s.x = fmaf(E, s.x, t4.x);
    s.y = fmaf(E, s.y, t4.y);
    s.z = fmaf(E, s.z, t4.z);
    s.w = fmaf(E, s.w, t4.w);
  }
}

// ---------------------------------------------------------------------------
// chunk_output (MFMA): G = Cc@Bc^T, CS = Cc@Sin (via SinT), mask G->W(bf16),
// Y = exp(csum)*CS + W@X (via XT) + D*x, silu(z) gate -> PACKED bf16 Ypk.
// 24 MFMA/wave, all exp/mask math f32.
// ---------------------------------------------------------------------------
__global__ __launch_bounds__(256) void chunk_output_kernel(
    const float* __restrict__ proj, const float* __restrict__ BC,
    const float2* __restrict__ aDT, const float* __restrict__ Sinbuf,
    const float* __restrict__ Dv, unsigned short* __restrict__ Ybf) {
  const int blk = blockIdx.x;
  const int c = blk & (NCH - 1), bh = blk >> 4;
  const int b = bh / NHEADS, hh = bh % NHEADS;
  const int tid = threadIdx.x;

  __shared__ unsigned short Cc[64 * LSTR];    // [t][n]
  __shared__ unsigned short Bc[64 * LSTR];    // [s][n]
  __shared__ unsigned short SinT[64 * LSTR];  // [p][n]
  __shared__ unsigned short XT[64 * LSTR];    // [p][s]
  __shared__ unsigned short Wl[64 * LSTR];    // [t][s]
  __shared__ float csum[QC];
  __shared__ float DTs[QC];

  if (tid < 64) {
    float2 ad = aDT[((size_t)bh << 10) + c * QC + tid];
    csum[tid] = wave_prefix_incl(ad.x, tid);
    DTs[tid] = ad.y;
  }

  const size_t sin_base = (size_t)blk * 4096;
  for (int i = tid; i < 1024; i += 256) {
    int s = i >> 4;
    int q = (i & 15) * 4;
    int r = b * SEQ + c * QC + s;
    float4 bv = *(const float4*)(BC + (size_t)r * 128 + q);
    float4 cv = *(const float4*)(BC + (size_t)r * 128 + 64 + q);
    float4 xv = *(const float4*)(proj + (size_t)r * D_PROJ + D_INNER + hh * 64 + q);
    float4 sv = *(const float4*)(Sinbuf + sin_base + (size_t)s * 64 + q);
    ushort4 cb, bb;
    cb.x = f2bf(cv.x); cb.y = f2bf(cv.y); cb.z = f2bf(cv.z); cb.w = f2bf(cv.w);
    bb.x = f2bf(bv.x); bb.y = f2bf(bv.y); bb.z = f2bf(bv.z); bb.w = f2bf(bv.w);
    *(ushort4*)&Cc[s * LSTR + q] = cb;
    *(ushort4*)&Bc[s * LSTR + q] = bb;
    XT[(q + 0) * LSTR + s] = f2bf(xv.x);
    XT[(q + 1) * LSTR + s] = f2bf(xv.y);
    XT[(q + 2) * LSTR + s] = f2bf(xv.z);
    XT[(q + 3) * LSTR + s] = f2bf(xv.w);
    SinT[(q + 0) * LSTR + s] = f2bf(sv.x);
    SinT[(q + 1) * LSTR + s] = f2bf(sv.y);
    SinT[(q + 2) * LSTR + s] = f2bf(sv.z);
    SinT[(q + 3) * LSTR + s] = f2bf(sv.w);
  }
  __syncthreads();

  const int w = tid >> 6, l = tid & 63;
  const int r16 = l & 15, g = l >> 4;

  f32x4 accg[4], accy[4];
#pragma unroll
  for (int i = 0; i < 4; ++i) {
    accg[i] = (f32x4){0.f, 0.f, 0.f, 0.f};
    accy[i] = (f32x4){0.f, 0.f, 0.f, 0.f};
  }

  // phase 1: G[t][s] and CS[t][p], inner dim n
#pragma unroll
  for (int kk = 0; kk < 2; ++kk) {
    short8 a = *(const short8*)&Cc[(w * 16 + r16) * LSTR + kk * 32 + g * 8];
#pragma unroll
    for (int f = 0; f < 4; ++f) {
      short8 bf = *(const short8*)&Bc[(f * 16 + r16) * LSTR + kk * 32 + g * 8];
      accg[f] = __builtin_amdgcn_mfma_f32_16x16x32_bf16(a, bf, accg[f], 0, 0, 0);
    }
#pragma unroll
    for (int f = 0; f < 4; ++f) {
      short8 bf = *(const short8*)&SinT[(f * 16 + r16) * LSTR + kk * 32 + g * 8];
      accy[f] = __builtin_amdgcn_mfma_f32_16x16x32_bf16(a, bf, accy[f], 0, 0, 0);
    }
  }

  // mask + decay -> W (bf16, LDS); scale CS by exp(csum_t)
  float cst[4], dsc[4];
#pragma unroll
  for (int q = 0; q < 4; ++q) {
    cst[q] = csum[w * 16 + g * 4 + q];
    dsc[q] = __expf(cst[q]);
  }
#pragma unroll
  for (int sf = 0; sf < 4; ++sf) {
    int s = sf * 16 + r16;
    float cs_s = csum[s], dt_s = DTs[s];
#pragma unroll
    for (int q = 0; q < 4; ++q) {
      int t = w * 16 + g * 4 + q;
      float wv = (s <= t) ? accg[sf][q] * __expf(cst[q] - cs_s) * dt_s : 0.f;
      Wl[t * LSTR + s] = f2bf(wv);
    }
  }
#pragma unroll
  for (int f = 0; f < 4; ++f)
#pragma unroll
    for (int q = 0; q < 4; ++q) accy[f][q] *= dsc[q];
  __syncthreads();

  // phase 2: Y[t][p] += sum_s W[t][s] * X[s][p]
#pragma unroll
  for (int kk = 0; kk < 2; ++kk) {
    short8 a = *(const short8*)&Wl[(w * 16 + r16) * LSTR + kk * 32 + g * 8];
#pragma unroll
    for (int f = 0; f < 4; ++f) {
      short8 bf = *(const short8*)&XT[(f * 16 + r16) * LSTR + kk * 32 + g * 8];
      accy[f] = __builtin_amdgcn_mfma_f32_16x16x32_bf16(a, bf, accy[f], 0, 0, 0);
    }
  }

  // epilogue: + D*x, silu(z), packed bf16 write
  const float Dh = Dv[hh];
  const int rg = b * 16 + c;
#pragma unroll
  for (int pf = 0; pf < 4; ++pf) {
    int p = pf * 16 + r16;
    int col = hh * 64 + p;
    int kt = col >> 5;
    int cseg = (col >> 3) & 3;
    int jj = p & 7;
    size_t base = ((size_t)(kt * RG_U + rg) * 4 + cseg) * 512 + jj;
#pragma unroll
    for (int q = 0; q < 4; ++q) {
      int t = w * 16 + g * 4 + q;
      int rr = b * SEQ + c * QC + t;
      float x = proj[(size_t)rr * D_PROJ + D_INNER + hh * 64 + p];
      float z = proj[(size_t)rr * D_PROJ + hh * 64 + p];
      float y = accy[pf][q] + Dh * x;
      Ybf[base + (size_t)t * 8] = f2bf(y * (z / (1.f + __expf(-z))));
    }
  }
}

// ---------------------------------------------------------------------------
// Launch
// ---------------------------------------------------------------------------
extern "C" void kernel_launch(void* const* d_in, const int* in_sizes, int n_in,
                              void* d_out, int out_size, void* d_ws, size_t ws_size,
                              hipStream_t stream) {
  const float* u       = (const float*)d_in[0];
  const float* Win     = (const float*)d_in[1];
  const float* Wout    = (const float*)d_in[2];
  const float* dt_bias = (const float*)d_in[3];
  const float* Dv      = (const float*)d_in[4];
  const float* Bg      = (const float*)d_in[5];
  const float* Bb      = (const float*)d_in[6];
  const float* Cg      = (const float*)d_in[7];
  const float* Cb      = (const float*)d_in[8];
  float* out = (float*)d_out;

  float* ws = (float*)d_ws;
  float*  proj    = ws;                                   // 2048*3248
  float*  BC      = proj + (size_t)ROWS * D_PROJ;         // 2048*128
  float*  aDTf    = BC + (size_t)ROWS * 128;              // 48*1024*2
  float2* aDT     = (float2*)aDTf;
  float*  Tbuf    = aDTf + (size_t)2 * BATCH * NHEADS * SEQ;        // 768*4096 f32
  float*  Ebuf    = Tbuf + (size_t)BATCH * NHEADS * NCH * 4096;     // 1024
  float*  Sinbuf  = Ebuf + 1024;                          // 768*4096 f32
  float*  Woutbff = Sinbuf + (size_t)BATCH * NHEADS * NCH * 4096;   // Wopk region
  float*  Pbuf    = Woutbff + 589824;                     // 2 * 2048*768 f32 partials

  // packed bf16 buffers aliased onto dead f32 regions (lifetimes verified):
  unsigned short* upk   = (unsigned short*)Sinbuf;   // dead before interchunk
  unsigned short* Winpk = (unsigned short*)Tbuf;     // dead before chunk_state
  unsigned short* Ypk   = (unsigned short*)Tbuf;     // after interchunk read Tbuf
  unsigned short* Wopk  = (unsigned short*)Woutbff;  // standalone

  // cast+pack (one fused launch)
  pack_all_kernel<<<KT_1 * RG_U + KT_1 * RG_WIN + KT_2 * RG_WO, 256, 0, stream>>>(
      u, Win, Wout, upk, Winpk, Wopk);

  // 1) proj = u @ Win.T   (128x128 tile)
  gemm_bt_bf16<128, 128, 26, 16, false><<<416, 256, 0, stream>>>(
      upk, Winpk, proj, RG_U, RG_WIN, ROWS, D_PROJ, D_MODEL);

  // 2) LN(B), LN(C), a/DT
  prep_kernel<<<ROWS, 64, 0, stream>>>(proj, dt_bias, Bg, Bb, Cg, Cb, BC, aDT);

  // 3) chunked scan (MFMA chunk kernels)
  chunk_state_kernel<<<BATCH * NHEADS * NCH, 256, 0, stream>>>(proj, BC, aDT, Tbuf, Ebuf);
  interchunk_kernel<<<BATCH * NHEADS * 4, 256, 0, stream>>>(Tbuf, Ebuf, Sinbuf);
  chunk_output_kernel<<<BATCH * NHEADS * NCH, 256, 0, stream>>>(proj, BC, aDT, Sinbuf, Dv, Ypk);

  // 4) out = Y @ Wout.T   (split-K=2: partials -> reduce)
  gemm_bt_bf16<64, 64, 12, 32, true><<<dim3(384, 2), 256, 0, stream>>>(
      Ypk, Wopk, Pbuf, RG_U, RG_WO, ROWS, D_MODEL, D_INNER / 2);
  reduce2_kernel<<<1536, 256, 0, stream>>>(Pbuf, out, ROWS * D_MODEL / 4);
}

// Round 11
// 81.420 us; speedup vs baseline: 1.5770x; 1.0054x over previous
//
#include <hip/hip_runtime.h>
#include <cstdint>

#define D_MODEL   768
#define D_STATE   64
#define D_INNER   1536
#define NHEADS    24
#define HEADDIM   64
#define D_PROJ    3248
#define BATCH     2
#define SEQ       1024
#define ROWS      (BATCH*SEQ)   // 2048
#define LN_EPS    1e-5f
#define A_FLOOR   1e-4f
#define QC        64            // chunk length
#define NCH       (SEQ/QC)      // 16
#define LSTR      72            // LDS row stride in shorts (144B = 9*16B)

// packed-operand geometry: [kt][rg][c4][64 rows][8 bf16] (4KB per (kt,rg))
#define RG_U    32
#define RG_WIN  52
#define RG_WO   12
#define KT_1    24
#define KT_2    48

typedef __attribute__((ext_vector_type(8))) short short8;
typedef __attribute__((ext_vector_type(4))) float f32x4;

__device__ __forceinline__ unsigned short f2bf(float f) {
  union { float f; uint32_t u; } v; v.f = f;
  uint32_t r = (v.u + 0x7FFFu + ((v.u >> 16) & 1u)) >> 16;
  return (unsigned short)r;
}
__device__ __forceinline__ float bf2f(unsigned short u) {
  union { uint32_t u; float f; } v; v.u = (uint32_t)u << 16;
  return v.f;
}
__device__ __forceinline__ void storeC(float v, float* p) { *p = v; }
__device__ __forceinline__ void storeC(float v, unsigned short* p) { *p = f2bf(v); }

__device__ __forceinline__ void gload_lds16(const void* g, void* l) {
  __builtin_amdgcn_global_load_lds(
      (const __attribute__((address_space(1))) unsigned int*)g,
      (__attribute__((address_space(3))) unsigned int*)l, 16, 0, 0);
}

template <int N>
__device__ __forceinline__ void wait_vm() {
  static_assert(N == 0 || N == 2 || N == 3 || N == 4 || N == 6 || N == 8,
                "unsupported vmcnt");
  if constexpr (N == 0) asm volatile("s_waitcnt vmcnt(0)" ::: "memory");
  else if constexpr (N == 2) asm volatile("s_waitcnt vmcnt(2)" ::: "memory");
  else if constexpr (N == 3) asm volatile("s_waitcnt vmcnt(3)" ::: "memory");
  else if constexpr (N == 4) asm volatile("s_waitcnt vmcnt(4)" ::: "memory");
  else if constexpr (N == 6) asm volatile("s_waitcnt vmcnt(6)" ::: "memory");
  else if constexpr (N == 8) asm volatile("s_waitcnt vmcnt(8)" ::: "memory");
}

// ---------------------------------------------------------------------------
// Pack f32 row-major -> bf16 [kt][rg][c][64][8].
// ---------------------------------------------------------------------------
__global__ __launch_bounds__(256) void pack_all_kernel(
    const float* __restrict__ u, const float* __restrict__ Win,
    const float* __restrict__ Wout, unsigned short* __restrict__ upk,
    unsigned short* __restrict__ Winpk, unsigned short* __restrict__ Wopk) {
  int b = blockIdx.x;
  const float* src; unsigned short* dst; int K, RG, kt, rg, srcRows;
  if (b < KT_1 * RG_U) {
    src = u; dst = upk; K = 768; RG = RG_U; kt = b / RG_U; rg = b % RG_U; srcRows = ROWS;
  } else if (b < KT_1 * RG_U + KT_1 * RG_WIN) {
    int i = b - KT_1 * RG_U;
    src = Win; dst = Winpk; K = 768; RG = RG_WIN; kt = i / RG_WIN; rg = i % RG_WIN; srcRows = D_PROJ;
  } else {
    int i = b - KT_1 * RG_U - KT_1 * RG_WIN;
    src = Wout; dst = Wopk; K = 1536; RG = RG_WO; kt = i / RG_WO; rg = i % RG_WO; srcRows = D_MODEL;
  }
  const int t = threadIdx.x;
  const int lr = t >> 2, cq = t & 3;
  const int R = rg * 64 + lr;
  float4 v0 = make_float4(0.f, 0.f, 0.f, 0.f), v1 = v0;
  if (R < srcRows) {
    const float* p = src + (size_t)R * K + kt * 32 + cq * 8;
    v0 = *(const float4*)p;
    v1 = *(const float4*)(p + 4);
  }
  ushort4 oa, ob;
  oa.x = f2bf(v0.x); oa.y = f2bf(v0.y); oa.z = f2bf(v0.z); oa.w = f2bf(v0.w);
  ob.x = f2bf(v1.x); ob.y = f2bf(v1.y); ob.z = f2bf(v1.z); ob.w = f2bf(v1.w);
  unsigned short* o = dst + ((size_t)(kt * RG + rg) * 4 + cq) * 512 + lr * 8;
  *(ushort4*)o = oa;
  *(ushort4*)(o + 4) = ob;
}

// ---------------------------------------------------------------------------
// MFMA bf16 GEMM (NT), packed operands, 4-buf/prefetch-3/1 barrier, XCD
// swizzle, optional split-K. CT = f32 or bf16 output.
// ---------------------------------------------------------------------------
template <int TBM, int TBN, int GX, int GY, bool XMAJOR, typename CT>
__global__ __launch_bounds__(256) void gemm_bt_bf16(
    const unsigned short* __restrict__ A, const unsigned short* __restrict__ B,
    CT* __restrict__ C, int aRG, int bRG, int M, int N, int K) {
  constexpr int MF = TBM / 32;
  constexpr int NF = TBN / 32;
  constexpr int NSA = TBM / 16;
  constexpr int NSB = TBN / 16;
  constexpr int LPW = (NSA + NSB) / 4;
  static_assert((NSA + NSB) % 4 == 0, "segments must split evenly over waves");
  constexpr int NWG = GX * GY;
  constexpr int PER = NWG / 8;
  static_assert(NWG % 8 == 0, "grid must split evenly over 8 XCDs");
  __shared__ unsigned short Asm[4][TBM * 32];
  __shared__ unsigned short Bsm[4][TBN * 32];

  const int tid = threadIdx.x;
  const int wv = tid >> 6, lane = tid & 63;
  const int kTiles = K >> 5;

  const int sk = blockIdx.y;
  A += (size_t)sk * kTiles * aRG * 2048;
  B += (size_t)sk * kTiles * bRG * 2048;
  C += (size_t)sk * M * N;

  const int g = (blockIdx.x & 7) * PER + (blockIdx.x >> 3);
  int bx, by;
  if constexpr (XMAJOR) { by = g / GX; bx = g - by * GX; }
  else                  { bx = g / GY; by = g - bx * GY; }
  const int bm = by * TBM, bn = bx * TBN;

  const int wm = (wv & 1) * (TBM / 2);
  const int wn = (wv >> 1) * (TBN / 2);
  const int gq = lane >> 4, r = lane & 15;

  f32x4 acc[MF][NF];
#pragma unroll
  for (int i = 0; i < MF; ++i)
#pragma unroll
    for (int j = 0; j < NF; ++j) acc[i][j] = (f32x4){0.f, 0.f, 0.f, 0.f};

  auto stage = [&](int kt, int buf) {
    for (int s = wv; s < NSA + NSB; s += 4) {
      if (s < NSA) {
        const unsigned short* src =
            A + ((size_t)kt * aRG + (bm >> 6) + (s >> 2)) * 2048 + (s & 3) * 512 + lane * 8;
        gload_lds16(src, (void*)(&Asm[buf][s * 512]));
      } else {
        int s2 = s - NSA;
        const unsigned short* src =
            B + ((size_t)kt * bRG + (bn >> 6) + (s2 >> 2)) * 2048 + (s2 & 3) * 512 + lane * 8;
        gload_lds16(src, (void*)(&Bsm[buf][s2 * 512]));
      }
    }
  };

  stage(0, 0);
  stage(1, 1);
  stage(2, 2);

  for (int t = 0; t < kTiles; ++t) {
    const int cur = t & 3;
    if (t + 2 < kTiles)      wait_vm<2 * LPW>();
    else if (t + 1 < kTiles) wait_vm<LPW>();
    else                     wait_vm<0>();
    __builtin_amdgcn_s_barrier();
    asm volatile("" ::: "memory");

    if (t + 3 < kTiles) stage(t + 3, (t + 3) & 3);

    short8 a[MF], b[NF];
#pragma unroll
    for (int mf = 0; mf < MF; ++mf) {
      int ra = wm + mf * 16 + r;
      a[mf] = *(const short8*)&Asm[cur][(ra >> 6) * 2048 + gq * 512 + (ra & 63) * 8];
    }
#pragma unroll
    for (int nf = 0; nf < NF; ++nf) {
      int rb = wn + nf * 16 + r;
      b[nf] = *(const short8*)&Bsm[cur][(rb >> 6) * 2048 + gq * 512 + (rb & 63) * 8];
    }
#pragma unroll
    for (int mf = 0; mf < MF; ++mf)
#pragma unroll
      for (int nf = 0; nf < NF; ++nf)
        acc[mf][nf] = __builtin_amdgcn_mfma_f32_16x16x32_bf16(a[mf], b[nf], acc[mf][nf], 0, 0, 0);
  }

#pragma unroll
  for (int mf = 0; mf < MF; ++mf) {
#pragma unroll
    for (int nf = 0; nf < NF; ++nf) {
      int col = bn + wn + nf * 16 + r;
      if (col < N) {
#pragma unroll
        for (int q = 0; q < 4; ++q) {
          int row = bm + wm + mf * 16 + gq * 4 + q;
          storeC(acc[mf][nf][q], &C[(size_t)row * N + col]);
        }
      }
    }
  }
}

// ---------------------------------------------------------------------------
// split-K reduce: out = p0 + p1
// ---------------------------------------------------------------------------
__global__ __launch_bounds__(256) void reduce2_kernel(
    const float* __restrict__ P, float* __restrict__ out, int n4) {
  int i = blockIdx.x * 256 + threadIdx.x;
  if (i < n4) {
    float4 a = *(const float4*)(P + (size_t)i * 4);
    float4 b = *(const float4*)(P + (size_t)(n4 + i) * 4);
    a.x += b.x; a.y += b.y; a.z += b.z; a.w += b.w;
    *(float4*)(out + (size_t)i * 4) = a;
  }
}

// ---------------------------------------------------------------------------
// Prep: LN(B), LN(C) -> BC (bf16); a=A*DT, DT -> aDT. proj is bf16.
// 256 threads = 4 waves, one row per wave. grid = ROWS/4.
// ---------------------------------------------------------------------------
__device__ __forceinline__ float softplusf(float x) {
  return (x > 20.f) ? x : log1pf(expf(x));
}
__device__ __forceinline__ float wave_sum64(float v) {
#pragma unroll
  for (int o = 32; o > 0; o >>= 1) v += __shfl_xor(v, o);
  return v;
}

__global__ __launch_bounds__(256) void prep_kernel(
    const unsigned short* __restrict__ proj, const float* __restrict__ dt_bias,
    const float* __restrict__ Bg, const float* __restrict__ Bb,
    const float* __restrict__ Cg, const float* __restrict__ Cb,
    unsigned short* __restrict__ BC, float2* __restrict__ aDT) {
  const int r = blockIdx.x * 4 + (threadIdx.x >> 6);
  const int lane = threadIdx.x & 63;
  const unsigned short* p = proj + (size_t)r * D_PROJ;

  float bp = bf2f(p[2 * D_INNER + lane]);
  float cp = bf2f(p[2 * D_INNER + D_STATE + lane]);

  float mb = wave_sum64(bp) * (1.f / 64.f);
  float mc = wave_sum64(cp) * (1.f / 64.f);
  float db = bp - mb, dc = cp - mc;
  float vb = wave_sum64(db * db) * (1.f / 64.f);
  float vc = wave_sum64(dc * dc) * (1.f / 64.f);
  float bn = db * rsqrtf(vb + LN_EPS) * Bg[lane] + Bb[lane];
  float cn = dc * rsqrtf(vc + LN_EPS) * Cg[lane] + Cb[lane];
  BC[(size_t)r * 128 + lane]      = f2bf(bn);
  BC[(size_t)r * 128 + 64 + lane] = f2bf(cn);

  if (lane < NHEADS) {
    float ddt = bf2f(p[2 * D_INNER + 2 * D_STATE + lane]);
    float dA  = bf2f(p[2 * D_INNER + 2 * D_STATE + NHEADS + lane]);
    float DT = softplusf(ddt + dt_bias[lane]);
    float Aa = fminf(-softplusf(dA), -A_FLOOR);
    int b = r >> 10;
    int t = r & 1023;
    aDT[((size_t)(b * NHEADS + lane) << 10) + t] = make_float2(Aa * DT, DT);
  }
}

__device__ __forceinline__ float wave_prefix_incl(float v, int lane) {
#pragma unroll
  for (int o = 1; o < 64; o <<= 1) {
    float w = __shfl_up(v, o);
    if (lane >= o) v += w;
  }
  return v;
}

// ---------------------------------------------------------------------------
// chunk_state (MFMA): T[n][p] = sum_s B[s][n] * (coeff_s * x[s][p])
// proj/BC bf16: B transposes as raw bits; x converts for coeff multiply.
// ---------------------------------------------------------------------------
__global__ __launch_bounds__(256) void chunk_state_kernel(
    const unsigned short* __restrict__ proj, const unsigned short* __restrict__ BC,
    const float2* __restrict__ aDT, float* __restrict__ Tbuf,
    float* __restrict__ Ebuf) {
  const int blk = blockIdx.x;
  const int c = blk & (NCH - 1), bh = blk >> 4;
  const int b = bh / NHEADS, hh = bh % NHEADS;
  const int tid = threadIdx.x;

  __shared__ unsigned short BT[64 * LSTR];  // [n][s]
  __shared__ unsigned short XT[64 * LSTR];  // [p][s]
  __shared__ float coeff[QC];
  __shared__ float etot[1];

  if (tid < 64) {
    float2 ad = aDT[((size_t)bh << 10) + c * QC + tid];
    float cs = wave_prefix_incl(ad.x, tid);
    float tot = __shfl(cs, 63);
    coeff[tid] = ad.y * __expf(tot - cs);
    if (tid == 63) etot[0] = __expf(tot);
  }
  __syncthreads();

  for (int i = tid; i < 1024; i += 256) {
    int s = i >> 4;
    int q = (i & 15) * 4;
    int r = b * SEQ + c * QC + s;
    ushort4 bv = *(const ushort4*)(BC + (size_t)r * 128 + q);
    ushort4 xv = *(const ushort4*)(proj + (size_t)r * D_PROJ + D_INNER + hh * 64 + q);
    float cf = coeff[s];
    BT[(q + 0) * LSTR + s] = bv.x;
    BT[(q + 1) * LSTR + s] = bv.y;
    BT[(q + 2) * LSTR + s] = bv.z;
    BT[(q + 3) * LSTR + s] = bv.w;
    XT[(q + 0) * LSTR + s] = f2bf(bf2f(xv.x) * cf);
    XT[(q + 1) * LSTR + s] = f2bf(bf2f(xv.y) * cf);
    XT[(q + 2) * LSTR + s] = f2bf(bf2f(xv.z) * cf);
    XT[(q + 3) * LSTR + s] = f2bf(bf2f(xv.w) * cf);
  }
  __syncthreads();

  const int w = tid >> 6, l = tid & 63;
  const int r16 = l & 15, g = l >> 4;
  f32x4 acc[4];
#pragma unroll
  for (int i = 0; i < 4; ++i) acc[i] = (f32x4){0.f, 0.f, 0.f, 0.f};

#pragma unroll
  for (int kk = 0; kk < 2; ++kk) {
    short8 a = *(const short8*)&BT[(w * 16 + r16) * LSTR + kk * 32 + g * 8];
#pragma unroll
    for (int pf = 0; pf < 4; ++pf) {
      short8 bf = *(const short8*)&XT[(pf * 16 + r16) * LSTR + kk * 32 + g * 8];
      acc[pf] = __builtin_amdgcn_mfma_f32_16x16x32_bf16(a, bf, acc[pf], 0, 0, 0);
    }
  }

  float* T = Tbuf + (size_t)blk * 4096;
#pragma unroll
  for (int pf = 0; pf < 4; ++pf)
#pragma unroll
    for (int q = 0; q < 4; ++q)
      T[(size_t)(w * 16 + g * 4 + q) * 64 + pf * 16 + r16] = acc[pf][q];
  if (tid == 0) Ebuf[blk] = etot[0];
}

// ---------------------------------------------------------------------------
// interchunk: S_in[c+1] = E_c * S_in[c] + T_c
// ---------------------------------------------------------------------------
__global__ __launch_bounds__(256) void interchunk_kernel(
    const float* __restrict__ Tbuf, const float* __restrict__ Ebuf,
    float* __restrict__ Sinbuf) {
  const int bh = blockIdx.x >> 2, part = blockIdx.x & 3;
  const int tid = threadIdx.x;
  const size_t eo = (size_t)part * 1024 + tid * 4;
  float4 s = make_float4(0.f, 0.f, 0.f, 0.f);
#pragma unroll
  for (int c = 0; c < NCH; ++c) {
    size_t off = ((size_t)(bh * NCH + c)) * 4096 + eo;
    *(float4*)(Sinbuf + off) = s;
    float E = Ebuf[bh * NCH + c];
    float4 t4 = *(const float4*)(Tbuf + off);
    s.x = fmaf(E, s.x, t4.x);
    s.y = fmaf(E, s.y, t4.y);
    s.z = fmaf(E, s.z, t4.z);
    s.w = fmaf(E, s.w, t4.w);
  }
}

// ---------------------------------------------------------------------------
// chunk_output (MFMA): G=Cc@Bc^T, CS=Cc@SinT, mask G->W, Y=exp*CS+W@X+D*x,
// silu(z) gate -> PACKED bf16 Ypk. proj/BC bf16 (raw-bit staging).
// ---------------------------------------------------------------------------
__global__ __launch_bounds__(256) void chunk_output_kernel(
    const unsigned short* __restrict__ proj, const unsigned short* __restrict__ BC,
    const float2* __restrict__ aDT, const float* __restrict__ Sinbuf,
    const float* __restrict__ Dv, unsigned short* __restrict__ Ybf) {
  const int blk = blockIdx.x;
  const int c = blk & (NCH - 1), bh = blk >> 4;
  const int b = bh / NHEADS, hh = bh % NHEADS;
  const int tid = threadIdx.x;

  __shared__ unsigned short Cc[64 * LSTR];    // [t][n]
  __shared__ unsigned short Bc[64 * LSTR];    // [s][n]
  __shared__ unsigned short SinT[64 * LSTR];  // [p][n]
  __shared__ unsigned short XT[64 * LSTR];    // [p][s]
  __shared__ unsigned short Wl[64 * LSTR];    // [t][s]
  __shared__ float csum[QC];
  __shared__ float DTs[QC];

  if (tid < 64) {
    float2 ad = aDT[((size_t)bh << 10) + c * QC + tid];
    csum[tid] = wave_prefix_incl(ad.x, tid);
    DTs[tid] = ad.y;
  }

  const size_t sin_base = (size_t)blk * 4096;
  for (int i = tid; i < 1024; i += 256) {
    int s = i >> 4;
    int q = (i & 15) * 4;
    int r = b * SEQ + c * QC + s;
    ushort4 bv = *(const ushort4*)(BC + (size_t)r * 128 + q);
    ushort4 cv = *(const ushort4*)(BC + (size_t)r * 128 + 64 + q);
    ushort4 xv = *(const ushort4*)(proj + (size_t)r * D_PROJ + D_INNER + hh * 64 + q);
    float4 sv = *(const float4*)(Sinbuf + sin_base + (size_t)s * 64 + q);
    *(ushort4*)&Cc[s * LSTR + q] = cv;
    *(ushort4*)&Bc[s * LSTR + q] = bv;
    XT[(q + 0) * LSTR + s] = xv.x;
    XT[(q + 1) * LSTR + s] = xv.y;
    XT[(q + 2) * LSTR + s] = xv.z;
    XT[(q + 3) * LSTR + s] = xv.w;
    SinT[(q + 0) * LSTR + s] = f2bf(sv.x);
    SinT[(q + 1) * LSTR + s] = f2bf(sv.y);
    SinT[(q + 2) * LSTR + s] = f2bf(sv.z);
    SinT[(q + 3) * LSTR + s] = f2bf(sv.w);
  }
  __syncthreads();

  const int w = tid >> 6, l = tid & 63;
  const int r16 = l & 15, g = l >> 4;

  f32x4 accg[4], accy[4];
#pragma unroll
  for (int i = 0; i < 4; ++i) {
    accg[i] = (f32x4){0.f, 0.f, 0.f, 0.f};
    accy[i] = (f32x4){0.f, 0.f, 0.f, 0.f};
  }

#pragma unroll
  for (int kk = 0; kk < 2; ++kk) {
    short8 a = *(const short8*)&Cc[(w * 16 + r16) * LSTR + kk * 32 + g * 8];
#pragma unroll
    for (int f = 0; f < 4; ++f) {
      short8 bf = *(const short8*)&Bc[(f * 16 + r16) * LSTR + kk * 32 + g * 8];
      accg[f] = __builtin_amdgcn_mfma_f32_16x16x32_bf16(a, bf, accg[f], 0, 0, 0);
    }
#pragma unroll
    for (int f = 0; f < 4; ++f) {
      short8 bf = *(const short8*)&SinT[(f * 16 + r16) * LSTR + kk * 32 + g * 8];
      accy[f] = __builtin_amdgcn_mfma_f32_16x16x32_bf16(a, bf, accy[f], 0, 0, 0);
    }
  }

  float cst[4], dsc[4];
#pragma unroll
  for (int q = 0; q < 4; ++q) {
    cst[q] = csum[w * 16 + g * 4 + q];
    dsc[q] = __expf(cst[q]);
  }
#pragma unroll
  for (int sf = 0; sf < 4; ++sf) {
    int s = sf * 16 + r16;
    float cs_s = csum[s], dt_s = DTs[s];
#pragma unroll
    for (int q = 0; q < 4; ++q) {
      int t = w * 16 + g * 4 + q;
      float wv = (s <= t) ? accg[sf][q] * __expf(cst[q] - cs_s) * dt_s : 0.f;
      Wl[t * LSTR + s] = f2bf(wv);
    }
  }
#pragma unroll
  for (int f = 0; f < 4; ++f)
#pragma unroll
    for (int q = 0; q < 4; ++q) accy[f][q] *= dsc[q];
  __syncthreads();

#pragma unroll
  for (int kk = 0; kk < 2; ++kk) {
    short8 a = *(const short8*)&Wl[(w * 16 + r16) * LSTR + kk * 32 + g * 8];
#pragma unroll
    for (int f = 0; f < 4; ++f) {
      short8 bf = *(const short8*)&XT[(f * 16 + r16) * LSTR + kk * 32 + g * 8];
      accy[f] = __builtin_amdgcn_mfma_f32_16x16x32_bf16(a, bf, accy[f], 0, 0, 0);
    }
  }

  const float Dh = Dv[hh];
  const int rg = b * 16 + c;
#pragma unroll
  for (int pf = 0; pf < 4; ++pf) {
    int p = pf * 16 + r16;
    int col = hh * 64 + p;
    int kt = col >> 5;
    int cseg = (col >> 3) & 3;
    int jj = p & 7;
    size_t base = ((size_t)(kt * RG_U + rg) * 4 + cseg) * 512 + jj;
#pragma unroll
    for (int q = 0; q < 4; ++q) {
      int t = w * 16 + g * 4 + q;
      int rr = b * SEQ + c * QC + t;
      float x = bf2f(proj[(size_t)rr * D_PROJ + D_INNER + hh * 64 + p]);
      float z = bf2f(proj[(size_t)rr * D_PROJ + hh * 64 + p]);
      float y = accy[pf][q] + Dh * x;
      Ybf[base + (size_t)t * 8] = f2bf(y * (z / (1.f + __expf(-z))));
    }
  }
}

// ---------------------------------------------------------------------------
// Launch
// ---------------------------------------------------------------------------
extern "C" void kernel_launch(void* const* d_in, const int* in_sizes, int n_in,
                              void* d_out, int out_size, void* d_ws, size_t ws_size,
                              hipStream_t stream) {
  const float* u       = (const float*)d_in[0];
  const float* Win     = (const float*)d_in[1];
  const float* Wout    = (const float*)d_in[2];
  const float* dt_bias = (const float*)d_in[3];
  const float* Dv      = (const float*)d_in[4];
  const float* Bg      = (const float*)d_in[5];
  const float* Bb      = (const float*)d_in[6];
  const float* Cg      = (const float*)d_in[7];
  const float* Cb      = (const float*)d_in[8];
  float* out = (float*)d_out;

  float* ws = (float*)d_ws;
  // bf16 proj (2048*3248 ushorts = 3,325,952 floats) and bf16 BC (131,072 floats)
  unsigned short* projsh = (unsigned short*)ws;
  float*  after_proj = ws + (size_t)ROWS * D_PROJ / 2;
  unsigned short* BCsh = (unsigned short*)after_proj;
  float*  aDTf    = after_proj + (size_t)ROWS * 128 / 2;
  float2* aDT     = (float2*)aDTf;
  float*  Tbuf    = aDTf + (size_t)2 * BATCH * NHEADS * SEQ;        // 3.14M floats
  float*  Ebuf    = Tbuf + (size_t)BATCH * NHEADS * NCH * 4096;     // 1024
  float*  Sinbuf  = Ebuf + 1024;                                    // 3.14M floats
  float*  Woutbff = Sinbuf + (size_t)BATCH * NHEADS * NCH * 4096;   // Wopk region
  float*  Pbuf    = Woutbff + 589824;                               // 3.14M floats

  // packed bf16 buffers aliased onto dead f32 regions (lifetimes verified):
  unsigned short* upk   = (unsigned short*)Sinbuf;   // dead before interchunk
  unsigned short* Winpk = (unsigned short*)Tbuf;     // dead before chunk_state
  unsigned short* Ypk   = (unsigned short*)Tbuf;     // after interchunk read Tbuf
  unsigned short* Wopk  = (unsigned short*)Woutbff;  // standalone

  // cast+pack (one fused launch)
  pack_all_kernel<<<KT_1 * RG_U + KT_1 * RG_WIN + KT_2 * RG_WO, 256, 0, stream>>>(
      u, Win, Wout, upk, Winpk, Wopk);

  // 1) proj = u @ Win.T  -> bf16 proj
  gemm_bt_bf16<128, 128, 26, 16, false><<<416, 256, 0, stream>>>(
      upk, Winpk, projsh, RG_U, RG_WIN, ROWS, D_PROJ, D_MODEL);

  // 2) LN(B), LN(C) -> bf16 BC; a/DT
  prep_kernel<<<ROWS / 4, 256, 0, stream>>>(projsh, dt_bias, Bg, Bb, Cg, Cb, BCsh, aDT);

  // 3) chunked scan (MFMA chunk kernels)
  chunk_state_kernel<<<BATCH * NHEADS * NCH, 256, 0, stream>>>(projsh, BCsh, aDT, Tbuf, Ebuf);
  interchunk_kernel<<<BATCH * NHEADS * 4, 256, 0, stream>>>(Tbuf, Ebuf, Sinbuf);
  chunk_output_kernel<<<BATCH * NHEADS * NCH, 256, 0, stream>>>(projsh, BCsh, aDT, Sinbuf, Dv, Ypk);

  // 4) out = Y @ Wout.T  (split-K=2 -> reduce)
  gemm_bt_bf16<64, 64, 12, 32, true><<<dim3(384, 2), 256, 0, stream>>>(
      Ypk, Wopk, Pbuf, RG_U, RG_WO, ROWS, D_MODEL, D_INNER / 2);
  reduce2_kernel<<<1536, 256, 0, stream>>>(Pbuf, out, ROWS * D_MODEL / 4);
}

// Round 12
// 78.864 us; speedup vs baseline: 1.6281x; 1.0324x over previous
//
#include <hip/hip_runtime.h>
#include <cstdint>

#define D_MODEL   768
#define D_STATE   64
#define D_INNER   1536
#define NHEADS    24
#define HEADDIM   64
#define D_PROJ    3248
#define BATCH     2
#define SEQ       1024
#define ROWS      (BATCH*SEQ)   // 2048
#define LN_EPS    1e-5f
#define A_FLOOR   1e-4f
#define QC        64            // chunk length
#define NCH       (SEQ/QC)      // 16
#define LSTR      72            // LDS row stride in shorts (144B = 9*16B)

// packed-operand geometry: [kt][rg][c4][64 rows][8 bf16] (4KB per (kt,rg))
#define RG_U    32
#define RG_WIN  52
#define RG_WO   12
#define KT_1    24
#define KT_2    48

typedef __attribute__((ext_vector_type(8))) short short8;
typedef __attribute__((ext_vector_type(4))) float f32x4;

__device__ __forceinline__ unsigned short f2bf(float f) {
  union { float f; uint32_t u; } v; v.f = f;
  uint32_t r = (v.u + 0x7FFFu + ((v.u >> 16) & 1u)) >> 16;
  return (unsigned short)r;
}
__device__ __forceinline__ float bf2f(unsigned short u) {
  union { uint32_t u; float f; } v; v.u = (uint32_t)u << 16;
  return v.f;
}
__device__ __forceinline__ void storeC(float v, float* p) { *p = v; }
__device__ __forceinline__ void storeC(float v, unsigned short* p) { *p = f2bf(v); }

__device__ __forceinline__ void gload_lds16(const void* g, void* l) {
  __builtin_amdgcn_global_load_lds(
      (const __attribute__((address_space(1))) unsigned int*)g,
      (__attribute__((address_space(3))) unsigned int*)l, 16, 0, 0);
}

template <int N>
__device__ __forceinline__ void wait_vm() {
  static_assert(N == 0 || N == 2 || N == 3 || N == 4 || N == 6 || N == 8,
                "unsupported vmcnt");
  if constexpr (N == 0) asm volatile("s_waitcnt vmcnt(0)" ::: "memory");
  else if constexpr (N == 2) asm volatile("s_waitcnt vmcnt(2)" ::: "memory");
  else if constexpr (N == 3) asm volatile("s_waitcnt vmcnt(3)" ::: "memory");
  else if constexpr (N == 4) asm volatile("s_waitcnt vmcnt(4)" ::: "memory");
  else if constexpr (N == 6) asm volatile("s_waitcnt vmcnt(6)" ::: "memory");
  else if constexpr (N == 8) asm volatile("s_waitcnt vmcnt(8)" ::: "memory");
}

// ---------------------------------------------------------------------------
// Pack f32 row-major -> bf16 [kt][rg][c][64][8].
// ---------------------------------------------------------------------------
__global__ __launch_bounds__(256) void pack_all_kernel(
    const float* __restrict__ u, const float* __restrict__ Win,
    const float* __restrict__ Wout, unsigned short* __restrict__ upk,
    unsigned short* __restrict__ Winpk, unsigned short* __restrict__ Wopk) {
  int b = blockIdx.x;
  const float* src; unsigned short* dst; int K, RG, kt, rg, srcRows;
  if (b < KT_1 * RG_U) {
    src = u; dst = upk; K = 768; RG = RG_U; kt = b / RG_U; rg = b % RG_U; srcRows = ROWS;
  } else if (b < KT_1 * RG_U + KT_1 * RG_WIN) {
    int i = b - KT_1 * RG_U;
    src = Win; dst = Winpk; K = 768; RG = RG_WIN; kt = i / RG_WIN; rg = i % RG_WIN; srcRows = D_PROJ;
  } else {
    int i = b - KT_1 * RG_U - KT_1 * RG_WIN;
    src = Wout; dst = Wopk; K = 1536; RG = RG_WO; kt = i / RG_WO; rg = i % RG_WO; srcRows = D_MODEL;
  }
  const int t = threadIdx.x;
  const int lr = t >> 2, cq = t & 3;
  const int R = rg * 64 + lr;
  float4 v0 = make_float4(0.f, 0.f, 0.f, 0.f), v1 = v0;
  if (R < srcRows) {
    const float* p = src + (size_t)R * K + kt * 32 + cq * 8;
    v0 = *(const float4*)p;
    v1 = *(const float4*)(p + 4);
  }
  ushort4 oa, ob;
  oa.x = f2bf(v0.x); oa.y = f2bf(v0.y); oa.z = f2bf(v0.z); oa.w = f2bf(v0.w);
  ob.x = f2bf(v1.x); ob.y = f2bf(v1.y); ob.z = f2bf(v1.z); ob.w = f2bf(v1.w);
  unsigned short* o = dst + ((size_t)(kt * RG + rg) * 4 + cq) * 512 + lr * 8;
  *(ushort4*)o = oa;
  *(ushort4*)(o + 4) = ob;
}

// ---------------------------------------------------------------------------
// MFMA bf16 GEMM (NT), packed operands. 3-buffer / prefetch-distance-2 /
// ONE barrier per K-iter. XCD panel swizzle. SPLIT=2: in-block split-K with
// 2*256 threads (waves 0-3 = K-half 0, waves 4-7 = K-half 1 on private LDS
// pipelines), f32 partial merge via LDS in epilogue (replaces reduce kernel).
// WAR safety: stage(t+2) targets buf[(t+2)%3] = buf[(t-1)%3]; all waves
// finished reading it during iter t-1, proven by the iter-t barrier.
// ---------------------------------------------------------------------------
template <int TBM, int TBN, int GX, int GY, bool XMAJOR, int SPLIT, typename CT>
__global__ __launch_bounds__(256 * SPLIT) void gemm_bt_bf16(
    const unsigned short* __restrict__ A, const unsigned short* __restrict__ B,
    CT* __restrict__ C, int aRG, int bRG, int M, int N, int K) {
  constexpr int MF = TBM / 32;
  constexpr int NF = TBN / 32;
  constexpr int NSA = TBM / 16;
  constexpr int NSB = TBN / 16;
  constexpr int LPW = (NSA + NSB) / 4;
  static_assert((NSA + NSB) % 4 == 0, "segments must split evenly over waves");
  constexpr int NWG = GX * GY;
  constexpr int PER = NWG / 8;
  static_assert(NWG % 8 == 0, "grid must split evenly over 8 XCDs");
  __shared__ unsigned short Asm[SPLIT][3][TBM * 32];
  __shared__ unsigned short Bsm[SPLIT][3][TBN * 32];

  const int tid = threadIdx.x;
  const int w = tid >> 6, lane = tid & 63;
  const int khalf = w >> 2;        // 0 for SPLIT=1
  const int wv = w & 3;
  const int kTiles = (K / SPLIT) >> 5;
  const int ktBase = khalf * kTiles;

  const int g = (blockIdx.x & 7) * PER + (blockIdx.x >> 3);
  int bx, by;
  if constexpr (XMAJOR) { by = g / GX; bx = g - by * GX; }
  else                  { bx = g / GY; by = g - bx * GY; }
  const int bm = by * TBM, bn = bx * TBN;

  const int wm = (wv & 1) * (TBM / 2);
  const int wn = (wv >> 1) * (TBN / 2);
  const int gq = lane >> 4, r = lane & 15;

  f32x4 acc[MF][NF];
#pragma unroll
  for (int i = 0; i < MF; ++i)
#pragma unroll
    for (int j = 0; j < NF; ++j) acc[i][j] = (f32x4){0.f, 0.f, 0.f, 0.f};

  auto stage = [&](int t, int buf) {
    const int kt = ktBase + t;
    for (int s = wv; s < NSA + NSB; s += 4) {
      if (s < NSA) {
        const unsigned short* src =
            A + ((size_t)kt * aRG + (bm >> 6) + (s >> 2)) * 2048 + (s & 3) * 512 + lane * 8;
        gload_lds16(src, (void*)(&Asm[khalf][buf][s * 512]));
      } else {
        int s2 = s - NSA;
        const unsigned short* src =
            B + ((size_t)kt * bRG + (bn >> 6) + (s2 >> 2)) * 2048 + (s2 & 3) * 512 + lane * 8;
        gload_lds16(src, (void*)(&Bsm[khalf][buf][s2 * 512]));
      }
    }
  };

  stage(0, 0);
  stage(1, 1);

  int cur = 0;
  for (int t = 0; t < kTiles; ++t) {
    if (t + 1 < kTiles) wait_vm<LPW>();   // tile t landed; t+1 may be in flight
    else                wait_vm<0>();
    __builtin_amdgcn_s_barrier();
    asm volatile("" ::: "memory");        // fence: s_barrier is IntrNoMem

    if (t + 2 < kTiles) stage(t + 2, (t + 2) % 3);

    short8 a[MF], b[NF];
#pragma unroll
    for (int mf = 0; mf < MF; ++mf) {
      int ra = wm + mf * 16 + r;
      a[mf] = *(const short8*)&Asm[khalf][cur][(ra >> 6) * 2048 + gq * 512 + (ra & 63) * 8];
    }
#pragma unroll
    for (int nf = 0; nf < NF; ++nf) {
      int rb = wn + nf * 16 + r;
      b[nf] = *(const short8*)&Bsm[khalf][cur][(rb >> 6) * 2048 + gq * 512 + (rb & 63) * 8];
    }
#pragma unroll
    for (int mf = 0; mf < MF; ++mf)
#pragma unroll
      for (int nf = 0; nf < NF; ++nf)
        acc[mf][nf] = __builtin_amdgcn_mfma_f32_16x16x32_bf16(a[mf], b[nf], acc[mf][nf], 0, 0, 0);

    cur = (cur + 1) % 3;
  }

  if constexpr (SPLIT == 2) {
    // merge K-half partials through LDS (16 KB region in half-0's A buffers)
    __syncthreads();
    float* red = (float*)&Asm[0][0][0];
    if (khalf == 1) {
#pragma unroll
      for (int mf = 0; mf < MF; ++mf)
#pragma unroll
        for (int nf = 0; nf < NF; ++nf)
#pragma unroll
          for (int q = 0; q < 4; ++q)
            red[(size_t)wv * 1024 + ((mf * NF + nf) * 4 + q) * 64 + lane] = acc[mf][nf][q];
    }
    __syncthreads();
    if (khalf == 1) return;
#pragma unroll
    for (int mf = 0; mf < MF; ++mf)
#pragma unroll
      for (int nf = 0; nf < NF; ++nf)
#pragma unroll
        for (int q = 0; q < 4; ++q)
          acc[mf][nf][q] += red[(size_t)wv * 1024 + ((mf * NF + nf) * 4 + q) * 64 + lane];
  }

  // C write: D row = (lane>>4)*4 + q, col = lane&15 (m89-verified layout)
#pragma unroll
  for (int mf = 0; mf < MF; ++mf) {
#pragma unroll
    for (int nf = 0; nf < NF; ++nf) {
      int col = bn + wn + nf * 16 + r;
      if (col < N) {
#pragma unroll
        for (int q = 0; q < 4; ++q) {
          int row = bm + wm + mf * 16 + gq * 4 + q;
          storeC(acc[mf][nf][q], &C[(size_t)row * N + col]);
        }
      }
    }
  }
}

// ---------------------------------------------------------------------------
// Prep: LN(B), LN(C) -> BC (bf16); a=A*DT, DT -> aDT. proj is bf16.
// ---------------------------------------------------------------------------
__device__ __forceinline__ float softplusf(float x) {
  return (x > 20.f) ? x : log1pf(expf(x));
}
__device__ __forceinline__ float wave_sum64(float v) {
#pragma unroll
  for (int o = 32; o > 0; o >>= 1) v += __shfl_xor(v, o);
  return v;
}

__global__ __launch_bounds__(256) void prep_kernel(
    const unsigned short* __restrict__ proj, const float* __restrict__ dt_bias,
    const float* __restrict__ Bg, const float* __restrict__ Bb,
    const float* __restrict__ Cg, const float* __restrict__ Cb,
    unsigned short* __restrict__ BC, float2* __restrict__ aDT) {
  const int r = blockIdx.x * 4 + (threadIdx.x >> 6);
  const int lane = threadIdx.x & 63;
  const unsigned short* p = proj + (size_t)r * D_PROJ;

  float bp = bf2f(p[2 * D_INNER + lane]);
  float cp = bf2f(p[2 * D_INNER + D_STATE + lane]);

  float mb = wave_sum64(bp) * (1.f / 64.f);
  float mc = wave_sum64(cp) * (1.f / 64.f);
  float db = bp - mb, dc = cp - mc;
  float vb = wave_sum64(db * db) * (1.f / 64.f);
  float vc = wave_sum64(dc * dc) * (1.f / 64.f);
  float bn = db * rsqrtf(vb + LN_EPS) * Bg[lane] + Bb[lane];
  float cn = dc * rsqrtf(vc + LN_EPS) * Cg[lane] + Cb[lane];
  BC[(size_t)r * 128 + lane]      = f2bf(bn);
  BC[(size_t)r * 128 + 64 + lane] = f2bf(cn);

  if (lane < NHEADS) {
    float ddt = bf2f(p[2 * D_INNER + 2 * D_STATE + lane]);
    float dA  = bf2f(p[2 * D_INNER + 2 * D_STATE + NHEADS + lane]);
    float DT = softplusf(ddt + dt_bias[lane]);
    float Aa = fminf(-softplusf(dA), -A_FLOOR);
    int b = r >> 10;
    int t = r & 1023;
    aDT[((size_t)(b * NHEADS + lane) << 10) + t] = make_float2(Aa * DT, DT);
  }
}

__device__ __forceinline__ float wave_prefix_incl(float v, int lane) {
#pragma unroll
  for (int o = 1; o < 64; o <<= 1) {
    float w = __shfl_up(v, o);
    if (lane >= o) v += w;
  }
  return v;
}

// ---------------------------------------------------------------------------
// chunk_state (MFMA): T[n][p] = sum_s B[s][n] * (coeff_s * x[s][p])
// ---------------------------------------------------------------------------
__global__ __launch_bounds__(256) void chunk_state_kernel(
    const unsigned short* __restrict__ proj, const unsigned short* __restrict__ BC,
    const float2* __restrict__ aDT, float* __restrict__ Tbuf,
    float* __restrict__ Ebuf) {
  const int blk = blockIdx.x;
  const int c = blk & (NCH - 1), bh = blk >> 4;
  const int b = bh / NHEADS, hh = bh % NHEADS;
  const int tid = threadIdx.x;

  __shared__ unsigned short BT[64 * LSTR];  // [n][s]
  __shared__ unsigned short XT[64 * LSTR];  // [p][s]
  __shared__ float coeff[QC];
  __shared__ float etot[1];

  if (tid < 64) {
    float2 ad = aDT[((size_t)bh << 10) + c * QC + tid];
    float cs = wave_prefix_incl(ad.x, tid);
    float tot = __shfl(cs, 63);
    coeff[tid] = ad.y * __expf(tot - cs);
    if (tid == 63) etot[0] = __expf(tot);
  }
  __syncthreads();

  for (int i = tid; i < 1024; i += 256) {
    int s = i >> 4;
    int q = (i & 15) * 4;
    int r = b * SEQ + c * QC + s;
    ushort4 bv = *(const ushort4*)(BC + (size_t)r * 128 + q);
    ushort4 xv = *(const ushort4*)(proj + (size_t)r * D_PROJ + D_INNER + hh * 64 + q);
    float cf = coeff[s];
    BT[(q + 0) * LSTR + s] = bv.x;
    BT[(q + 1) * LSTR + s] = bv.y;
    BT[(q + 2) * LSTR + s] = bv.z;
    BT[(q + 3) * LSTR + s] = bv.w;
    XT[(q + 0) * LSTR + s] = f2bf(bf2f(xv.x) * cf);
    XT[(q + 1) * LSTR + s] = f2bf(bf2f(xv.y) * cf);
    XT[(q + 2) * LSTR + s] = f2bf(bf2f(xv.z) * cf);
    XT[(q + 3) * LSTR + s] = f2bf(bf2f(xv.w) * cf);
  }
  __syncthreads();

  const int w = tid >> 6, l = tid & 63;
  const int r16 = l & 15, g = l >> 4;
  f32x4 acc[4];
#pragma unroll
  for (int i = 0; i < 4; ++i) acc[i] = (f32x4){0.f, 0.f, 0.f, 0.f};

#pragma unroll
  for (int kk = 0; kk < 2; ++kk) {
    short8 a = *(const short8*)&BT[(w * 16 + r16) * LSTR + kk * 32 + g * 8];
#pragma unroll
    for (int pf = 0; pf < 4; ++pf) {
      short8 bf = *(const short8*)&XT[(pf * 16 + r16) * LSTR + kk * 32 + g * 8];
      acc[pf] = __builtin_amdgcn_mfma_f32_16x16x32_bf16(a, bf, acc[pf], 0, 0, 0);
    }
  }

  float* T = Tbuf + (size_t)blk * 4096;
#pragma unroll
  for (int pf = 0; pf < 4; ++pf)
#pragma unroll
    for (int q = 0; q < 4; ++q)
      T[(size_t)(w * 16 + g * 4 + q) * 64 + pf * 16 + r16] = acc[pf][q];
  if (tid == 0) Ebuf[blk] = etot[0];
}

// ---------------------------------------------------------------------------
// interchunk: S_in[c+1] = E_c * S_in[c] + T_c
// ---------------------------------------------------------------------------
__global__ __launch_bounds__(256) void interchunk_kernel(
    const float* __restrict__ Tbuf, const float* __restrict__ Ebuf,
    float* __restrict__ Sinbuf) {
  const int bh = blockIdx.x >> 2, part = blockIdx.x & 3;
  const int tid = threadIdx.x;
  const size_t eo = (size_t)part * 1024 + tid * 4;
  float4 s = make_float4(0.f, 0.f, 0.f, 0.f);
#pragma unroll
  for (int c = 0; c < NCH; ++c) {
    size_t off = ((size_t)(bh * NCH + c)) * 4096 + eo;
    *(float4*)(Sinbuf + off) = s;
    float E = Ebuf[bh * NCH + c];
    float4 t4 = *(const float4*)(Tbuf + off);
    s.x = fmaf(E, s.x, t4.x);
    s.y = fmaf(E, s.y, t4.y);
    s.z = fmaf(E, s.z, t4.z);
    s.w = fmaf(E, s.w, t4.w);
  }
}

// ---------------------------------------------------------------------------
// chunk_output (MFMA): G=Cc@Bc^T, CS=Cc@SinT, mask G->W, Y=exp*CS+W@X+D*x,
// silu(z) gate -> PACKED bf16 Ypk.
// ---------------------------------------------------------------------------
__global__ __launch_bounds__(256) void chunk_output_kernel(
    const unsigned short* __restrict__ proj, const unsigned short* __restrict__ BC,
    const float2* __restrict__ aDT, const float* __restrict__ Sinbuf,
    const float* __restrict__ Dv, unsigned short* __restrict__ Ybf) {
  const int blk = blockIdx.x;
  const int c = blk & (NCH - 1), bh = blk >> 4;
  const int b = bh / NHEADS, hh = bh % NHEADS;
  const int tid = threadIdx.x;

  __shared__ unsigned short Cc[64 * LSTR];    // [t][n]
  __shared__ unsigned short Bc[64 * LSTR];    // [s][n]
  __shared__ unsigned short SinT[64 * LSTR];  // [p][n]
  __shared__ unsigned short XT[64 * LSTR];    // [p][s]
  __shared__ unsigned short Wl[64 * LSTR];    // [t][s]
  __shared__ float csum[QC];
  __shared__ float DTs[QC];

  if (tid < 64) {
    float2 ad = aDT[((size_t)bh << 10) + c * QC + tid];
    csum[tid] = wave_prefix_incl(ad.x, tid);
    DTs[tid] = ad.y;
  }

  const size_t sin_base = (size_t)blk * 4096;
  for (int i = tid; i < 1024; i += 256) {
    int s = i >> 4;
    int q = (i & 15) * 4;
    int r = b * SEQ + c * QC + s;
    ushort4 bv = *(const ushort4*)(BC + (size_t)r * 128 + q);
    ushort4 cv = *(const ushort4*)(BC + (size_t)r * 128 + 64 + q);
    ushort4 xv = *(const ushort4*)(proj + (size_t)r * D_PROJ + D_INNER + hh * 64 + q);
    float4 sv = *(const float4*)(Sinbuf + sin_base + (size_t)s * 64 + q);
    *(ushort4*)&Cc[s * LSTR + q] = cv;
    *(ushort4*)&Bc[s * LSTR + q] = bv;
    XT[(q + 0) * LSTR + s] = xv.x;
    XT[(q + 1) * LSTR + s] = xv.y;
    XT[(q + 2) * LSTR + s] = xv.z;
    XT[(q + 3) * LSTR + s] = xv.w;
    SinT[(q + 0) * LSTR + s] = f2bf(sv.x);
    SinT[(q + 1) * LSTR + s] = f2bf(sv.y);
    SinT[(q + 2) * LSTR + s] = f2bf(sv.z);
    SinT[(q + 3) * LSTR + s] = f2bf(sv.w);
  }
  __syncthreads();

  const int w = tid >> 6, l = tid & 63;
  const int r16 = l & 15, g = l >> 4;

  f32x4 accg[4], accy[4];
#pragma unroll
  for (int i = 0; i < 4; ++i) {
    accg[i] = (f32x4){0.f, 0.f, 0.f, 0.f};
    accy[i] = (f32x4){0.f, 0.f, 0.f, 0.f};
  }

#pragma unroll
  for (int kk = 0; kk < 2; ++kk) {
    short8 a = *(const short8*)&Cc[(w * 16 + r16) * LSTR + kk * 32 + g * 8];
#pragma unroll
    for (int f = 0; f < 4; ++f) {
      short8 bf = *(const short8*)&Bc[(f * 16 + r16) * LSTR + kk * 32 + g * 8];
      accg[f] = __builtin_amdgcn_mfma_f32_16x16x32_bf16(a, bf, accg[f], 0, 0, 0);
    }
#pragma unroll
    for (int f = 0; f < 4; ++f) {
      short8 bf = *(const short8*)&SinT[(f * 16 + r16) * LSTR + kk * 32 + g * 8];
      accy[f] = __builtin_amdgcn_mfma_f32_16x16x32_bf16(a, bf, accy[f], 0, 0, 0);
    }
  }

  float cst[4], dsc[4];
#pragma unroll
  for (int q = 0; q < 4; ++q) {
    cst[q] = csum[w * 16 + g * 4 + q];
    dsc[q] = __expf(cst[q]);
  }
#pragma unroll
  for (int sf = 0; sf < 4; ++sf) {
    int s = sf * 16 + r16;
    float cs_s = csum[s], dt_s = DTs[s];
#pragma unroll
    for (int q = 0; q < 4; ++q) {
      int t = w * 16 + g * 4 + q;
      float wv = (s <= t) ? accg[sf][q] * __expf(cst[q] - cs_s) * dt_s : 0.f;
      Wl[t * LSTR + s] = f2bf(wv);
    }
  }
#pragma unroll
  for (int f = 0; f < 4; ++f)
#pragma unroll
    for (int q = 0; q < 4; ++q) accy[f][q] *= dsc[q];
  __syncthreads();

#pragma unroll
  for (int kk = 0; kk < 2; ++kk) {
    short8 a = *(const short8*)&Wl[(w * 16 + r16) * LSTR + kk * 32 + g * 8];
#pragma unroll
    for (int f = 0; f < 4; ++f) {
      short8 bf = *(const short8*)&XT[(f * 16 + r16) * LSTR + kk * 32 + g * 8];
      accy[f] = __builtin_amdgcn_mfma_f32_16x16x32_bf16(a, bf, accy[f], 0, 0, 0);
    }
  }

  const float Dh = Dv[hh];
  const int rg = b * 16 + c;
#pragma unroll
  for (int pf = 0; pf < 4; ++pf) {
    int p = pf * 16 + r16;
    int col = hh * 64 + p;
    int kt = col >> 5;
    int cseg = (col >> 3) & 3;
    int jj = p & 7;
    size_t base = ((size_t)(kt * RG_U + rg) * 4 + cseg) * 512 + jj;
#pragma unroll
    for (int q = 0; q < 4; ++q) {
      int t = w * 16 + g * 4 + q;
      int rr = b * SEQ + c * QC + t;
      float x = bf2f(proj[(size_t)rr * D_PROJ + D_INNER + hh * 64 + p]);
      float z = bf2f(proj[(size_t)rr * D_PROJ + hh * 64 + p]);
      float y = accy[pf][q] + Dh * x;
      Ybf[base + (size_t)t * 8] = f2bf(y * (z / (1.f + __expf(-z))));
    }
  }
}

// ---------------------------------------------------------------------------
// Launch
// ---------------------------------------------------------------------------
extern "C" void kernel_launch(void* const* d_in, const int* in_sizes, int n_in,
                              void* d_out, int out_size, void* d_ws, size_t ws_size,
                              hipStream_t stream) {
  const float* u       = (const float*)d_in[0];
  const float* Win     = (const float*)d_in[1];
  const float* Wout    = (const float*)d_in[2];
  const float* dt_bias = (const float*)d_in[3];
  const float* Dv      = (const float*)d_in[4];
  const float* Bg      = (const float*)d_in[5];
  const float* Bb      = (const float*)d_in[6];
  const float* Cg      = (const float*)d_in[7];
  const float* Cb      = (const float*)d_in[8];
  float* out = (float*)d_out;

  float* ws = (float*)d_ws;
  unsigned short* projsh = (unsigned short*)ws;
  float*  after_proj = ws + (size_t)ROWS * D_PROJ / 2;
  unsigned short* BCsh = (unsigned short*)after_proj;
  float*  aDTf    = after_proj + (size_t)ROWS * 128 / 2;
  float2* aDT     = (float2*)aDTf;
  float*  Tbuf    = aDTf + (size_t)2 * BATCH * NHEADS * SEQ;
  float*  Ebuf    = Tbuf + (size_t)BATCH * NHEADS * NCH * 4096;
  float*  Sinbuf  = Ebuf + 1024;
  float*  Woutbff = Sinbuf + (size_t)BATCH * NHEADS * NCH * 4096;

  // packed bf16 buffers aliased onto dead f32 regions (lifetimes verified):
  unsigned short* upk   = (unsigned short*)Sinbuf;   // dead before interchunk
  unsigned short* Winpk = (unsigned short*)Tbuf;     // dead before chunk_state
  unsigned short* Ypk   = (unsigned short*)Tbuf;     // after interchunk read Tbuf
  unsigned short* Wopk  = (unsigned short*)Woutbff;  // standalone

  // cast+pack (one fused launch)
  pack_all_kernel<<<KT_1 * RG_U + KT_1 * RG_WIN + KT_2 * RG_WO, 256, 0, stream>>>(
      u, Win, Wout, upk, Winpk, Wopk);

  // 1) proj = u @ Win.T  -> bf16 proj (128x128, 3-buf single-barrier)
  gemm_bt_bf16<128, 128, 26, 16, false, 1, unsigned short><<<416, 256, 0, stream>>>(
      upk, Winpk, projsh, RG_U, RG_WIN, ROWS, D_PROJ, D_MODEL);

  // 2) LN(B), LN(C) -> bf16 BC; a/DT
  prep_kernel<<<ROWS / 4, 256, 0, stream>>>(projsh, dt_bias, Bg, Bb, Cg, Cb, BCsh, aDT);

  // 3) chunked scan (MFMA chunk kernels)
  chunk_state_kernel<<<BATCH * NHEADS * NCH, 256, 0, stream>>>(projsh, BCsh, aDT, Tbuf, Ebuf);
  interchunk_kernel<<<BATCH * NHEADS * 4, 256, 0, stream>>>(Tbuf, Ebuf, Sinbuf);
  chunk_output_kernel<<<BATCH * NHEADS * NCH, 256, 0, stream>>>(projsh, BCsh, aDT, Sinbuf, Dv, Ypk);

  // 4) out = Y @ Wout.T  (in-block split-K=2, 512 threads, direct write)
  gemm_bt_bf16<64, 64, 12, 32, true, 2, float><<<384, 512, 0, stream>>>(
      Ypk, Wopk, out, RG_U, RG_WO, ROWS, D_MODEL, D_INNER);
}